// Round 1
// baseline (3216.877 us; speedup 1.0000x reference)
//
#include <hip/hip_runtime.h>

// ---------------------------------------------------------------------------
// MSHGAT forward: 2x GCNConv -> BatchNorm -> HGNN (2x SpMM) -> row softmax
//                 -> fc1 -> fusion gate.  N=50000, D=64, E=600000, NNZ=800000.
// All fp32. Scatter aggregation via global fp32 atomics (order nondeterminism
// ~1e-5, threshold 0.355).
// ---------------------------------------------------------------------------

// ---- degree / dinv --------------------------------------------------------
__global__ __launch_bounds__(256) void init_deg_kernel(float* deg, int n) {
    int i = blockIdx.x * 256 + threadIdx.x;
    if (i < n) deg[i] = 1.0f;                    // self-loop
}

__global__ __launch_bounds__(256) void accum_deg_kernel(const int* __restrict__ dst,
                                                        float* __restrict__ deg, int e) {
    int i = blockIdx.x * 256 + threadIdx.x;
    if (i < e) atomicAdd(&deg[dst[i]], 1.0f);
}

__global__ __launch_bounds__(256) void finalize_dinv_kernel(float* deg, int n) {
    int i = blockIdx.x * 256 + threadIdx.x;
    if (i < n) deg[i] = rsqrtf(fmaxf(deg[i], 1.0f));
}

// ---- small dense GEMM: out[N,M] = X[N,K] @ W (or W^T), W staged in LDS ----
template <int K, int M, bool TRANSB>
__global__ __launch_bounds__(256) void gemm_kernel(const float* __restrict__ X,
                                                   const float* __restrict__ W,
                                                   float* __restrict__ out, int nrows) {
    __shared__ float Wl[K * M];
    for (int i = threadIdx.x; i < K * M; i += 256) {
        int k = i / M, m = i - k * M;
        Wl[i] = TRANSB ? W[m * K + k] : W[i];
    }
    __syncthreads();
    constexpr int RPP = 256 / M;   // rows per pass
    constexpr int RPB = 2048 / M;  // rows per block
    int m = threadIdx.x % M;
    int rend = (blockIdx.x + 1) * RPB; if (rend > nrows) rend = nrows;
    for (int r = blockIdx.x * RPB + threadIdx.x / M; r < rend; r += RPP) {
        const float* xr = X + (long long)r * K;
        float acc = 0.0f;
#pragma unroll 8
        for (int k = 0; k < K; ++k) acc = fmaf(xr[k], Wl[k * M + m], acc);
        out[(long long)r * M + m] = acc;
    }
}

// ---- GCN: init h = b + dinv^2 * xw (self loop), then edge scatter ---------
template <int M>
__global__ __launch_bounds__(256) void gcn_init_kernel(const float* __restrict__ xw,
                                                       const float* __restrict__ dinv,
                                                       const float* __restrict__ b,
                                                       float* __restrict__ h, int total) {
    int idx = blockIdx.x * 256 + threadIdx.x;
    if (idx >= total) return;
    int i = idx / M, d = idx % M;
    float di = dinv[i];
    h[idx] = b[d] + di * di * xw[idx];
}

template <int M>
__global__ __launch_bounds__(256) void gcn_scatter_kernel(const float* __restrict__ xw,
                                                          const float* __restrict__ dinv,
                                                          const int* __restrict__ src,
                                                          const int* __restrict__ dst,
                                                          float* __restrict__ h, int nedges) {
    constexpr int TPE = M / 4;  // threads per edge (float4 each)
    int idx = blockIdx.x * 256 + threadIdx.x;
    int e = idx / TPE, c = idx % TPE;
    if (e >= nedges) return;
    int s = src[e], t = dst[e];
    float nrm = dinv[s] * dinv[t];
    const float4 v = *(const float4*)(xw + (long long)s * M + c * 4);
    float* p = h + (long long)t * M + c * 4;
    atomicAdd(p + 0, nrm * v.x);
    atomicAdd(p + 1, nrm * v.y);
    atomicAdd(p + 2, nrm * v.z);
    atomicAdd(p + 3, nrm * v.w);
}

// ---- BatchNorm (batch stats over N) ---------------------------------------
__global__ __launch_bounds__(256) void bn_stats_kernel(const float* __restrict__ h2,
                                                       float* __restrict__ stats,
                                                       int nrows, int rpb) {
    int col = threadIdx.x & 63;
    int grp = threadIdx.x >> 6;  // 0..3
    int r0 = blockIdx.x * rpb;
    int r1 = r0 + rpb; if (r1 > nrows) r1 = nrows;
    float s = 0.0f, s2 = 0.0f;
    for (int r = r0 + grp; r < r1; r += 4) {
        float v = h2[(long long)r * 64 + col];
        s += v; s2 += v * v;
    }
    __shared__ float ls[4][64], ls2[4][64];
    ls[grp][col] = s; ls2[grp][col] = s2;
    __syncthreads();
    if (grp == 0) {
        s  = ls[0][col] + ls[1][col] + ls[2][col] + ls[3][col];
        s2 = ls2[0][col] + ls2[1][col] + ls2[2][col] + ls2[3][col];
        atomicAdd(&stats[col], s);
        atomicAdd(&stats[64 + col], s2);
    }
}

__global__ __launch_bounds__(256) void bn_apply_kernel(float* __restrict__ h2,
                                                       const float* __restrict__ stats,
                                                       const float* __restrict__ gamma,
                                                       const float* __restrict__ beta,
                                                       const float* __restrict__ hbias,
                                                       float* __restrict__ xrelu,
                                                       int total, float invN) {
    int idx = blockIdx.x * 256 + threadIdx.x;
    if (idx >= total) return;
    int col = idx & 63;
    float mu = stats[col] * invN;
    float var = stats[64 + col] * invN - mu * mu;
    float v = (h2[idx] - mu) * rsqrtf(var + 1e-5f) * gamma[col] + beta[col];
    h2[idx] = v;                                  // hidden (kept for fusion)
    xrelu[idx] = fmaxf(v, 0.0f) + hbias[col];     // relu(hidden)+hgc1_bias
}

// ---- HGNN sparse scatter: out[rout[j]] += val[j] * in[rin[j]] --------------
__global__ __launch_bounds__(256) void hg_scatter_kernel(const float* __restrict__ in,
                                                         const float* __restrict__ val,
                                                         const int* __restrict__ rin,
                                                         const int* __restrict__ rout,
                                                         float* __restrict__ out, int nnz) {
    int idx = blockIdx.x * 256 + threadIdx.x;
    int j = idx >> 4, c = idx & 15;  // 16 threads/nnz, float4 each
    if (j >= nnz) return;
    float v = val[j];
    int a = rin[j], b = rout[j];
    const float4 x = *(const float4*)(in + (long long)a * 64 + c * 4);
    float* p = out + (long long)b * 64 + c * 4;
    atomicAdd(p + 0, v * x.x);
    atomicAdd(p + 1, v * x.y);
    atomicAdd(p + 2, v * x.z);
    atomicAdd(p + 3, v * x.w);
}

// ---- row softmax over D=64 (one wave per row) ------------------------------
__global__ __launch_bounds__(256) void softmax_rows_kernel(float* __restrict__ x, int nrows) {
    int row = blockIdx.x * 4 + (threadIdx.x >> 6);
    int lane = threadIdx.x & 63;
    if (row >= nrows) return;
    long long o = (long long)row * 64 + lane;
    float v = x[o];
    float m = v;
    for (int d = 32; d; d >>= 1) m = fmaxf(m, __shfl_xor(m, d, 64));
    float e = expf(v - m);
    float s = e;
    for (int d = 32; d; d >>= 1) s += __shfl_xor(s, d, 64);
    x[o] = e / s;
}

// ---- fusion gate: g=tanh(in@W1^T+b1); s=g.w2+b2; softmax over 2 branches ---
__global__ __launch_bounds__(256) void fusion_kernel(const float* __restrict__ hidden,
                                                     const float* __restrict__ subn,
                                                     const float* __restrict__ W1,   // [64,64] row-major [d][k]
                                                     const float* __restrict__ b1,
                                                     const float* __restrict__ w2,   // [64]
                                                     const float* __restrict__ b2,   // [1]
                                                     float* __restrict__ out, int nrows) {
    __shared__ float L[64 * 64];  // L[k*64+d] = W1[d*64+k]  (conflict-free reads)
    for (int i = threadIdx.x; i < 4096; i += 256) {
        int k = i >> 6, d = i & 63;
        L[i] = W1[d * 64 + k];
    }
    __syncthreads();
    int row = blockIdx.x * 4 + (threadIdx.x >> 6);
    if (row >= nrows) return;
    int d = threadIdx.x & 63;
    long long o = (long long)row * 64 + d;
    float hv = hidden[o];
    float sv = subn[o];
    float accH = b1[d], accS = b1[d];
#pragma unroll
    for (int k = 0; k < 64; ++k) {
        float lw = L[k * 64 + d];
        accH = fmaf(__shfl(hv, k, 64), lw, accH);
        accS = fmaf(__shfl(sv, k, 64), lw, accS);
    }
    float gH = tanhf(accH), gS = tanhf(accS);
    float w2d = w2[d];
    float sH = gH * w2d, sS = gS * w2d;
    for (int dd = 32; dd; dd >>= 1) {
        sH += __shfl_xor(sH, dd, 64);
        sS += __shfl_xor(sS, dd, 64);
    }
    sH += b2[0]; sS += b2[0];
    float mx = fmaxf(sH, sS);
    float eH = expf(sH - mx), eS = expf(sS - mx);
    float inv = 1.0f / (eH + eS);
    out[o] = (eH * hv + eS * sv) * inv;
}

// ---------------------------------------------------------------------------
extern "C" void kernel_launch(void* const* d_in, const int* in_sizes, int n_in,
                              void* d_out, int out_size, void* d_ws, size_t ws_size,
                              hipStream_t stream) {
    const float* emb       = (const float*)d_in[0];
    const float* W1        = (const float*)d_in[1];
    const float* b1        = (const float*)d_in[2];
    const float* W2        = (const float*)d_in[3];
    const float* b2        = (const float*)d_in[4];
    const float* gamma     = (const float*)d_in[5];
    const float* beta      = (const float*)d_in[6];
    const float* hgc1_bias = (const float*)d_in[7];
    const float* fc1_W     = (const float*)d_in[8];
    const float* fus_l1_W  = (const float*)d_in[9];
    const float* fus_l1_b  = (const float*)d_in[10];
    const float* fus_l2_W  = (const float*)d_in[11];
    const float* fus_l2_b  = (const float*)d_in[12];
    const float* hg_val    = (const float*)d_in[13];
    const int*   edge_index= (const int*)d_in[14];
    const int*   hg_row    = (const int*)d_in[15];
    const int*   hg_col    = (const int*)d_in[16];

    const int N   = in_sizes[0] / 64;
    const int E   = in_sizes[14] / 2;
    const int NNZ = in_sizes[13];
    const int* src = edge_index;
    const int* dst = edge_index + E;

    // workspace layout (floats): dinv[N] | buf1[128N] | buf2[128N] | stats[128]
    float* ws    = (float*)d_ws;
    float* dinv  = ws;
    float* buf1  = ws + N;
    float* buf2  = buf1 + (size_t)128 * N;
    float* stats = buf2 + (size_t)128 * N;

    float* xw1  = buf1;                      // N x 128
    float* h1   = buf2;                      // N x 128
    float* xw2  = buf1;                      // N x 64   (xw1 dead)
    float* h2   = buf1 + (size_t)64 * N;     // N x 64 -> hidden (lives to end)
    float* xre  = buf2;                      // N x 64   (h1 dead)
    float* eemb = buf2 + (size_t)64 * N;     // N x 64
    float* x2   = buf1;                      // N x 64   (xw2 dead)
    float* subn = buf2;                      // N x 64   (xre dead)
    float* out  = (float*)d_out;

    // --- degrees ---
    hipMemsetAsync(stats, 0, 128 * sizeof(float), stream);
    init_deg_kernel<<<(N + 255) / 256, 256, 0, stream>>>(dinv, N);
    accum_deg_kernel<<<(E + 255) / 256, 256, 0, stream>>>(dst, dinv, E);
    finalize_dinv_kernel<<<(N + 255) / 256, 256, 0, stream>>>(dinv, N);

    // --- GCN layer 1: [N,64] @ [64,128] then sym-norm aggregate ---
    gemm_kernel<64, 128, false><<<(N + 15) / 16, 256, 0, stream>>>(emb, W1, xw1, N);
    {
        int total = N * 128;
        gcn_init_kernel<128><<<(total + 255) / 256, 256, 0, stream>>>(xw1, dinv, b1, h1, total);
        int thr = E * 32;  // E * (128/4)
        gcn_scatter_kernel<128><<<(thr + 255) / 256, 256, 0, stream>>>(xw1, dinv, src, dst, h1, E);
    }

    // --- GCN layer 2: [N,128] @ [128,64] then aggregate ---
    gemm_kernel<128, 64, false><<<(N + 31) / 32, 256, 0, stream>>>(h1, W2, xw2, N);
    {
        int total = N * 64;
        gcn_init_kernel<64><<<(total + 255) / 256, 256, 0, stream>>>(xw2, dinv, b2, h2, total);
        int thr = E * 16;  // E * (64/4)
        gcn_scatter_kernel<64><<<(thr + 255) / 256, 256, 0, stream>>>(xw2, dinv, src, dst, h2, E);
    }

    // --- BatchNorm (batch stats) + relu + hgc1_bias ---
    {
        int nblocks = 256;
        int rpb = (N + nblocks - 1) / nblocks;
        bn_stats_kernel<<<nblocks, 256, 0, stream>>>(h2, stats, N, rpb);
        int total = N * 64;
        bn_apply_kernel<<<(total + 255) / 256, 256, 0, stream>>>(h2, stats, gamma, beta,
                                                                 hgc1_bias, xre, total, 1.0f / N);
    }

    // --- HGNN: edge = G^T x ; x = G edge ---
    hipMemsetAsync(eemb, 0, (size_t)64 * N * sizeof(float), stream);
    {
        int thr = NNZ * 16;
        hg_scatter_kernel<<<(thr + 255) / 256, 256, 0, stream>>>(xre, hg_val, hg_row, hg_col, eemb, NNZ);
    }
    hipMemsetAsync(x2, 0, (size_t)64 * N * sizeof(float), stream);
    {
        int thr = NNZ * 16;
        hg_scatter_kernel<<<(thr + 255) / 256, 256, 0, stream>>>(eemb, hg_val, hg_col, hg_row, x2, NNZ);
    }

    // --- row softmax + fc1 (x @ fc1_W^T) ---
    softmax_rows_kernel<<<(N + 3) / 4, 256, 0, stream>>>(x2, N);
    gemm_kernel<64, 64, true><<<(N + 31) / 32, 256, 0, stream>>>(x2, fc1_W, subn, N);

    // --- fusion gate ---
    fusion_kernel<<<(N + 3) / 4, 256, 0, stream>>>(h2, subn, fus_l1_W, fus_l1_b,
                                                   fus_l2_W, fus_l2_b, out, N);
}

// Round 2
// 1179.091 us; speedup vs baseline: 2.7283x; 2.7283x over previous
//
#include <hip/hip_runtime.h>

// ---------------------------------------------------------------------------
// MSHGAT forward, round 2: replace fp32 atomic scatters with device-built CSR
// + gather-sum (one wave per destination node, single write per output row).
// N=50000, D=64, E=600000, NNZ=800000. All fp32.
// ---------------------------------------------------------------------------

// ---- CSR build: histogram -> scan -> placement -----------------------------
__global__ __launch_bounds__(256) void hist_kernel(const int* __restrict__ key,
                                                   int* __restrict__ cnt, int n) {
    int i = blockIdx.x * 256 + threadIdx.x;
    if (i < n) atomicAdd(&cnt[key[i]], 1);
}

__global__ __launch_bounds__(256) void hg_hist_kernel(const int* __restrict__ row,
                                                      const int* __restrict__ col,
                                                      int* __restrict__ cntr,
                                                      int* __restrict__ cntc, int n) {
    int i = blockIdx.x * 256 + threadIdx.x;
    if (i < n) {
        atomicAdd(&cntr[row[i]], 1);
        atomicAdd(&cntc[col[i]], 1);
    }
}

// single-block exclusive scan of cnt[0..n) -> off[0..n], also copies to cur.
__global__ __launch_bounds__(1024) void scan_kernel(const int* __restrict__ cnt,
                                                    int* __restrict__ off,
                                                    int* __restrict__ cur, int n) {
    __shared__ int part[1024];
    int tid = threadIdx.x;
    int chunk = (n + 1023) / 1024;
    int s0 = tid * chunk, s1 = s0 + chunk;
    if (s1 > n) s1 = n;
    int sum = 0;
    for (int i = s0; i < s1; ++i) sum += cnt[i];
    part[tid] = sum;
    __syncthreads();
    for (int d = 1; d < 1024; d <<= 1) {
        int v = (tid >= d) ? part[tid - d] : 0;
        __syncthreads();
        part[tid] += v;
        __syncthreads();
    }
    int run = (tid == 0) ? 0 : part[tid - 1];
    for (int i = s0; i < s1; ++i) {
        int c = cnt[i];
        off[i] = run; cur[i] = run;
        run += c;
    }
    if (tid == 1023) off[n] = part[1023];
}

__global__ __launch_bounds__(256) void place_gcn_kernel(const int* __restrict__ src,
                                                        const int* __restrict__ dst,
                                                        int* __restrict__ cur,
                                                        int* __restrict__ srcs, int e) {
    int i = blockIdx.x * 256 + threadIdx.x;
    if (i >= e) return;
    int pos = atomicAdd(&cur[dst[i]], 1);
    srcs[pos] = src[i];
}

__global__ __launch_bounds__(256) void hg_place_kernel(const int* __restrict__ row,
                                                       const int* __restrict__ col,
                                                       const float* __restrict__ val,
                                                       int* __restrict__ curc,
                                                       int* __restrict__ curr,
                                                       int2* __restrict__ entc,
                                                       int2* __restrict__ entr, int n) {
    int i = blockIdx.x * 256 + threadIdx.x;
    if (i >= n) return;
    int r = row[i], c = col[i];
    int vb = __float_as_int(val[i]);
    int pc = atomicAdd(&curc[c], 1);
    entc[pc] = make_int2(r, vb);       // CSR by col: entry = (row, val)
    int pr = atomicAdd(&curr[r], 1);
    entr[pr] = make_int2(c, vb);       // CSR by row: entry = (col, val)
}

// dinv[i] = rsqrt(in_degree + 1)  (self loop)
__global__ __launch_bounds__(256) void dinv_kernel(const int* __restrict__ off,
                                                   float* __restrict__ dinv, int n) {
    int i = blockIdx.x * 256 + threadIdx.x;
    if (i < n) dinv[i] = rsqrtf((float)(off[i + 1] - off[i] + 1));
}

// ---- small dense GEMM: out[N,M] = X[N,K] @ W (or W^T), W staged in LDS -----
template <int K, int M, bool TRANSB>
__global__ __launch_bounds__(256) void gemm_kernel(const float* __restrict__ X,
                                                   const float* __restrict__ W,
                                                   float* __restrict__ out, int nrows) {
    __shared__ float Wl[K * M];
    for (int i = threadIdx.x; i < K * M; i += 256) {
        int k = i / M, m = i - k * M;
        Wl[i] = TRANSB ? W[m * K + k] : W[i];
    }
    __syncthreads();
    constexpr int RPP = 256 / M;
    constexpr int RPB = 2048 / M;
    int m = threadIdx.x % M;
    int rend = (blockIdx.x + 1) * RPB; if (rend > nrows) rend = nrows;
    for (int r = blockIdx.x * RPB + threadIdx.x / M; r < rend; r += RPP) {
        const float* xr = X + (long long)r * K;
        float acc = 0.0f;
#pragma unroll 8
        for (int k = 0; k < K; ++k) acc = fmaf(xr[k], Wl[k * M + m], acc);
        out[(long long)r * M + m] = acc;
    }
}

// ---- GCN gather: h[t] = b + dinv_t^2*xw[t] + sum_e dinv[s]*dinv_t*xw[s] ----
// one wave per node; M=128: lane owns float2; M=64: lane owns 1 float.
__global__ __launch_bounds__(256) void gcn_gather128_kernel(const float* __restrict__ xw,
                                                            const float* __restrict__ dinv,
                                                            const int* __restrict__ off,
                                                            const int* __restrict__ srcs,
                                                            const float* __restrict__ b,
                                                            float* __restrict__ h, int n) {
    int node = blockIdx.x * 4 + (threadIdx.x >> 6);
    if (node >= n) return;
    int lane = threadIdx.x & 63;
    int e0 = off[node], e1 = off[node + 1];
    float dt = dinv[node];
    float2 xs = *(const float2*)(xw + (long long)node * 128 + lane * 2);
    float2 acc = make_float2(dt * dt * xs.x, dt * dt * xs.y);
    int s = (e0 < e1) ? srcs[e0] : 0;
    float ds = (e0 < e1) ? dinv[s] : 0.0f;
    for (int e = e0; e < e1; ++e) {
        int s2 = (e + 1 < e1) ? srcs[e + 1] : 0;
        float ds2 = (e + 1 < e1) ? dinv[s2] : 0.0f;
        float2 v = *(const float2*)(xw + (long long)s * 128 + lane * 2);
        float nrm = ds * dt;
        acc.x = fmaf(nrm, v.x, acc.x);
        acc.y = fmaf(nrm, v.y, acc.y);
        s = s2; ds = ds2;
    }
    acc.x += b[lane * 2];
    acc.y += b[lane * 2 + 1];
    *(float2*)(h + (long long)node * 128 + lane * 2) = acc;
}

__global__ __launch_bounds__(256) void gcn_gather64_kernel(const float* __restrict__ xw,
                                                           const float* __restrict__ dinv,
                                                           const int* __restrict__ off,
                                                           const int* __restrict__ srcs,
                                                           const float* __restrict__ b,
                                                           float* __restrict__ h, int n) {
    int node = blockIdx.x * 4 + (threadIdx.x >> 6);
    if (node >= n) return;
    int lane = threadIdx.x & 63;
    int e0 = off[node], e1 = off[node + 1];
    float dt = dinv[node];
    float acc = dt * dt * xw[(long long)node * 64 + lane];
    int s = (e0 < e1) ? srcs[e0] : 0;
    float ds = (e0 < e1) ? dinv[s] : 0.0f;
    for (int e = e0; e < e1; ++e) {
        int s2 = (e + 1 < e1) ? srcs[e + 1] : 0;
        float ds2 = (e + 1 < e1) ? dinv[s2] : 0.0f;
        float v = xw[(long long)s * 64 + lane];
        acc = fmaf(ds * dt, v, acc);
        s = s2; ds = ds2;
    }
    h[(long long)node * 64 + lane] = acc + b[lane];
}

// ---- HGNN gather: out[t] = sum_e val_e * in[idx_e]  (D=64) -----------------
__global__ __launch_bounds__(256) void hg_gather_kernel(const float* __restrict__ in,
                                                        const int* __restrict__ off,
                                                        const int2* __restrict__ ents,
                                                        float* __restrict__ out, int n) {
    int node = blockIdx.x * 4 + (threadIdx.x >> 6);
    if (node >= n) return;
    int lane = threadIdx.x & 63;
    int e0 = off[node], e1 = off[node + 1];
    float acc = 0.0f;
    int2 t = (e0 < e1) ? ents[e0] : make_int2(0, 0);
    for (int e = e0; e < e1; ++e) {
        int2 t2 = (e + 1 < e1) ? ents[e + 1] : make_int2(0, 0);
        float v = in[(long long)t.x * 64 + lane];
        acc = fmaf(__int_as_float(t.y), v, acc);
        t = t2;
    }
    out[(long long)node * 64 + lane] = acc;
}

// ---- BatchNorm (batch stats over N) ----------------------------------------
__global__ __launch_bounds__(256) void bn_stats_kernel(const float* __restrict__ h2,
                                                       float* __restrict__ stats,
                                                       int nrows, int rpb) {
    int col = threadIdx.x & 63;
    int grp = threadIdx.x >> 6;
    int r0 = blockIdx.x * rpb;
    int r1 = r0 + rpb; if (r1 > nrows) r1 = nrows;
    float s = 0.0f, s2 = 0.0f;
    for (int r = r0 + grp; r < r1; r += 4) {
        float v = h2[(long long)r * 64 + col];
        s += v; s2 += v * v;
    }
    __shared__ float ls[4][64], ls2[4][64];
    ls[grp][col] = s; ls2[grp][col] = s2;
    __syncthreads();
    if (grp == 0) {
        s  = ls[0][col] + ls[1][col] + ls[2][col] + ls[3][col];
        s2 = ls2[0][col] + ls2[1][col] + ls2[2][col] + ls2[3][col];
        atomicAdd(&stats[col], s);
        atomicAdd(&stats[64 + col], s2);
    }
}

__global__ __launch_bounds__(256) void bn_apply_kernel(float* __restrict__ h2,
                                                       const float* __restrict__ stats,
                                                       const float* __restrict__ gamma,
                                                       const float* __restrict__ beta,
                                                       const float* __restrict__ hbias,
                                                       float* __restrict__ xrelu,
                                                       int total, float invN) {
    int idx = blockIdx.x * 256 + threadIdx.x;
    if (idx >= total) return;
    int col = idx & 63;
    float mu = stats[col] * invN;
    float var = stats[64 + col] * invN - mu * mu;
    float v = (h2[idx] - mu) * rsqrtf(var + 1e-5f) * gamma[col] + beta[col];
    h2[idx] = v;
    xrelu[idx] = fmaxf(v, 0.0f) + hbias[col];
}

// ---- row softmax over D=64 --------------------------------------------------
__global__ __launch_bounds__(256) void softmax_rows_kernel(float* __restrict__ x, int nrows) {
    int row = blockIdx.x * 4 + (threadIdx.x >> 6);
    int lane = threadIdx.x & 63;
    if (row >= nrows) return;
    long long o = (long long)row * 64 + lane;
    float v = x[o];
    float m = v;
    for (int d = 32; d; d >>= 1) m = fmaxf(m, __shfl_xor(m, d, 64));
    float e = expf(v - m);
    float s = e;
    for (int d = 32; d; d >>= 1) s += __shfl_xor(s, d, 64);
    x[o] = e / s;
}

// ---- fusion gate -------------------------------------------------------------
__global__ __launch_bounds__(256) void fusion_kernel(const float* __restrict__ hidden,
                                                     const float* __restrict__ subn,
                                                     const float* __restrict__ W1,
                                                     const float* __restrict__ b1,
                                                     const float* __restrict__ w2,
                                                     const float* __restrict__ b2,
                                                     float* __restrict__ out, int nrows) {
    __shared__ float L[64 * 64];  // L[k*64+d] = W1[d*64+k]
    for (int i = threadIdx.x; i < 4096; i += 256) {
        int k = i >> 6, d = i & 63;
        L[i] = W1[d * 64 + k];
    }
    __syncthreads();
    int row = blockIdx.x * 4 + (threadIdx.x >> 6);
    if (row >= nrows) return;
    int d = threadIdx.x & 63;
    long long o = (long long)row * 64 + d;
    float hv = hidden[o];
    float sv = subn[o];
    float accH = b1[d], accS = b1[d];
#pragma unroll
    for (int k = 0; k < 64; ++k) {
        float lw = L[k * 64 + d];
        accH = fmaf(__shfl(hv, k, 64), lw, accH);
        accS = fmaf(__shfl(sv, k, 64), lw, accS);
    }
    float gH = tanhf(accH), gS = tanhf(accS);
    float w2d = w2[d];
    float sH = gH * w2d, sS = gS * w2d;
    for (int dd = 32; dd; dd >>= 1) {
        sH += __shfl_xor(sH, dd, 64);
        sS += __shfl_xor(sS, dd, 64);
    }
    sH += b2[0]; sS += b2[0];
    float mx = fmaxf(sH, sS);
    float eH = expf(sH - mx), eS = expf(sS - mx);
    float inv = 1.0f / (eH + eS);
    out[o] = (eH * hv + eS * sv) * inv;
}

// ---------------------------------------------------------------------------
extern "C" void kernel_launch(void* const* d_in, const int* in_sizes, int n_in,
                              void* d_out, int out_size, void* d_ws, size_t ws_size,
                              hipStream_t stream) {
    const float* emb       = (const float*)d_in[0];
    const float* W1        = (const float*)d_in[1];
    const float* b1        = (const float*)d_in[2];
    const float* W2        = (const float*)d_in[3];
    const float* b2        = (const float*)d_in[4];
    const float* gamma     = (const float*)d_in[5];
    const float* beta      = (const float*)d_in[6];
    const float* hgc1_bias = (const float*)d_in[7];
    const float* fc1_W     = (const float*)d_in[8];
    const float* fus_l1_W  = (const float*)d_in[9];
    const float* fus_l1_b  = (const float*)d_in[10];
    const float* fus_l2_W  = (const float*)d_in[11];
    const float* fus_l2_b  = (const float*)d_in[12];
    const float* hg_val    = (const float*)d_in[13];
    const int*   edge_index= (const int*)d_in[14];
    const int*   hg_row    = (const int*)d_in[15];
    const int*   hg_col    = (const int*)d_in[16];

    const int N   = in_sizes[0] / 64;
    const int E   = in_sizes[14] / 2;
    const int NNZ = in_sizes[13];
    const int* src = edge_index;
    const int* dst = edge_index + E;

    // workspace layout (4B units), all region sizes kept even:
    // dinv N | buf1 128N | buf2 128N | stats 128 |
    // gcn_off N+2 | gcn_cur N | gcn_srcs E |
    // hgc_off N+2 | hgc_cur N | hgr_off N+2 | hgr_cur N |
    // hgc_ent 2*NNZ | hgr_ent 2*NNZ
    float* ws     = (float*)d_ws;
    float* dinv   = ws;
    float* buf1   = dinv + N;
    float* buf2   = buf1 + (size_t)128 * N;
    float* stats  = buf2 + (size_t)128 * N;
    int*   gcn_off = (int*)(stats + 128);
    int*   gcn_cur = gcn_off + (N + 2);
    int*   gcn_srcs= gcn_cur + N;
    int*   hgc_off = gcn_srcs + E;
    int*   hgc_cur = hgc_off + (N + 2);
    int*   hgr_off = hgc_cur + N;
    int*   hgr_cur = hgr_off + (N + 2);
    int2*  hgc_ent = (int2*)(hgr_cur + N);
    int2*  hgr_ent = hgc_ent + NNZ;

    float* xw1  = buf1;                      // N x 128
    float* h1   = buf2;                      // N x 128
    float* xw2  = buf1;                      // N x 64  (xw1 dead)
    float* h2   = buf1 + (size_t)64 * N;     // N x 64  -> hidden (lives to end)
    float* xre  = buf2;                      // N x 64  (h1 dead)
    float* eemb = buf2 + (size_t)64 * N;     // N x 64
    float* x2   = buf1;                      // N x 64  (xw2 dead)
    float* subn = buf2;                      // N x 64  (xre dead)
    float* out  = (float*)d_out;

    const int GB = 256;

    // --- CSR builds (gcn by dst; hg by col and by row) ---
    hipMemsetAsync(stats, 0, 128 * sizeof(float), stream);
    hipMemsetAsync(gcn_cur, 0, N * sizeof(int), stream);
    hipMemsetAsync(hgc_cur, 0, N * sizeof(int), stream);
    hipMemsetAsync(hgr_cur, 0, N * sizeof(int), stream);

    hist_kernel<<<(E + GB - 1) / GB, GB, 0, stream>>>(dst, gcn_cur, E);
    hg_hist_kernel<<<(NNZ + GB - 1) / GB, GB, 0, stream>>>(hg_row, hg_col, hgr_cur, hgc_cur, NNZ);

    scan_kernel<<<1, 1024, 0, stream>>>(gcn_cur, gcn_off, gcn_cur, N);
    scan_kernel<<<1, 1024, 0, stream>>>(hgc_cur, hgc_off, hgc_cur, N);
    scan_kernel<<<1, 1024, 0, stream>>>(hgr_cur, hgr_off, hgr_cur, N);

    dinv_kernel<<<(N + GB - 1) / GB, GB, 0, stream>>>(gcn_off, dinv, N);
    place_gcn_kernel<<<(E + GB - 1) / GB, GB, 0, stream>>>(src, dst, gcn_cur, gcn_srcs, E);
    hg_place_kernel<<<(NNZ + GB - 1) / GB, GB, 0, stream>>>(hg_row, hg_col, hg_val,
                                                            hgc_cur, hgr_cur, hgc_ent, hgr_ent, NNZ);

    // --- GCN layer 1: xw1 = emb @ W1 ; gather-aggregate ---
    gemm_kernel<64, 128, false><<<(N + 15) / 16, 256, 0, stream>>>(emb, W1, xw1, N);
    gcn_gather128_kernel<<<(N + 3) / 4, 256, 0, stream>>>(xw1, dinv, gcn_off, gcn_srcs, b1, h1, N);

    // --- GCN layer 2 ---
    gemm_kernel<128, 64, false><<<(N + 31) / 32, 256, 0, stream>>>(h1, W2, xw2, N);
    gcn_gather64_kernel<<<(N + 3) / 4, 256, 0, stream>>>(xw2, dinv, gcn_off, gcn_srcs, b2, h2, N);

    // --- BatchNorm + relu + hgc1_bias ---
    {
        int nblocks = 256;
        int rpb = (N + nblocks - 1) / nblocks;
        bn_stats_kernel<<<nblocks, 256, 0, stream>>>(h2, stats, N, rpb);
        int total = N * 64;
        bn_apply_kernel<<<(total + 255) / 256, 256, 0, stream>>>(h2, stats, gamma, beta,
                                                                 hgc1_bias, xre, total, 1.0f / N);
    }

    // --- HGNN: edge_emb[col] = sum val*x[row] ; x2[row] = sum val*edge_emb[col] ---
    hg_gather_kernel<<<(N + 3) / 4, 256, 0, stream>>>(xre, hgc_off, hgc_ent, eemb, N);
    hg_gather_kernel<<<(N + 3) / 4, 256, 0, stream>>>(eemb, hgr_off, hgr_ent, x2, N);

    // --- row softmax + fc1 ---
    softmax_rows_kernel<<<(N + 3) / 4, 256, 0, stream>>>(x2, N);
    gemm_kernel<64, 64, true><<<(N + 31) / 32, 256, 0, stream>>>(x2, fc1_W, subn, N);

    // --- fusion gate ---
    fusion_kernel<<<(N + 3) / 4, 256, 0, stream>>>(h2, subn, fus_l1_W, fus_l1_b,
                                                   fus_l2_W, fus_l2_b, out, N);
}

// Round 3
// 918.754 us; speedup vs baseline: 3.5013x; 1.2834x over previous
//
#include <hip/hip_runtime.h>

// ---------------------------------------------------------------------------
// MSHGAT forward, round 3:
//  - dinv folded into GEMM epilogue -> gathers are pure row-sums
//  - widened gathers (float4/lane, 2-4 edges per wave, shfl_xor reduce)
//  - fused tail (softmax + fc1 + fusion gate in one kernel)
//  - merged hist / scan kernels
// N=50000, D=64, E=600000, NNZ=800000. All fp32.
// ---------------------------------------------------------------------------

// ---- histograms (gcn by dst, hg by row and by col) -------------------------
__global__ __launch_bounds__(256) void hist_all_kernel(const int* __restrict__ dst, int e,
                                                       const int* __restrict__ row,
                                                       const int* __restrict__ col, int nnz,
                                                       int* __restrict__ cg,
                                                       int* __restrict__ cr,
                                                       int* __restrict__ cc) {
    int i = blockIdx.x * 256 + threadIdx.x;
    if (i < e) atomicAdd(&cg[dst[i]], 1);
    if (i < nnz) {
        atomicAdd(&cr[row[i]], 1);
        atomicAdd(&cc[col[i]], 1);
    }
}

// ---- 3 independent exclusive scans in one launch (block b -> array b) ------
// cnt is overwritten with running positions (doubles as "cur"); off[0..n].
// Block 0 additionally writes dinv[i] = rsqrt(indeg + 1).
__global__ __launch_bounds__(1024) void scan3_kernel(int* __restrict__ g_cnt, int* __restrict__ g_off,
                                                     int* __restrict__ c_cnt, int* __restrict__ c_off,
                                                     int* __restrict__ r_cnt, int* __restrict__ r_off,
                                                     float* __restrict__ dinv, int n) {
    int which = blockIdx.x;
    int* cnt = (which == 0) ? g_cnt : (which == 1) ? c_cnt : r_cnt;
    int* off = (which == 0) ? g_off : (which == 1) ? c_off : r_off;
    __shared__ int part[1024];
    int tid = threadIdx.x;
    int chunk = (n + 1023) / 1024;
    int s0 = tid * chunk, s1 = s0 + chunk;
    if (s1 > n) s1 = n;
    int sum = 0;
    for (int i = s0; i < s1; ++i) {
        int c = cnt[i];
        sum += c;
        if (which == 0) dinv[i] = rsqrtf((float)(c + 1));
    }
    part[tid] = sum;
    __syncthreads();
    for (int d = 1; d < 1024; d <<= 1) {
        int v = (tid >= d) ? part[tid - d] : 0;
        __syncthreads();
        part[tid] += v;
        __syncthreads();
    }
    int run = (tid == 0) ? 0 : part[tid - 1];
    for (int i = s0; i < s1; ++i) {
        int c = cnt[i];
        off[i] = run;
        cnt[i] = run;   // becomes "cur" for placement
        run += c;
    }
    if (tid == 1023) off[n] = part[1023];
}

// ---- placement -------------------------------------------------------------
__global__ __launch_bounds__(256) void place_gcn_kernel(const int* __restrict__ src,
                                                        const int* __restrict__ dst,
                                                        int* __restrict__ cur,
                                                        int* __restrict__ srcs, int e) {
    int i = blockIdx.x * 256 + threadIdx.x;
    if (i >= e) return;
    int pos = atomicAdd(&cur[dst[i]], 1);
    srcs[pos] = src[i];
}

__global__ __launch_bounds__(256) void hg_place_kernel(const int* __restrict__ row,
                                                       const int* __restrict__ col,
                                                       const float* __restrict__ val,
                                                       int* __restrict__ curc,
                                                       int* __restrict__ curr,
                                                       int2* __restrict__ entc,
                                                       int2* __restrict__ entr, int n) {
    int i = blockIdx.x * 256 + threadIdx.x;
    if (i >= n) return;
    int r = row[i], c = col[i];
    int vb = __float_as_int(val[i]);
    int pc = atomicAdd(&curc[c], 1);
    entc[pc] = make_int2(r, vb);       // CSR by col: entry = (row, val)
    int pr = atomicAdd(&curr[r], 1);
    entr[pr] = make_int2(c, vb);       // CSR by row: entry = (col, val)
}

// ---- small dense GEMM: out[N,M] = X[N,K] @ W, optional per-row scale -------
template <int K, int M, bool SCALE>
__global__ __launch_bounds__(256) void gemm_kernel(const float* __restrict__ X,
                                                   const float* __restrict__ W,
                                                   const float* __restrict__ rowscale,
                                                   float* __restrict__ out, int nrows) {
    __shared__ float Wl[K * M];
    for (int i = threadIdx.x; i < K * M; i += 256) Wl[i] = W[i];
    __syncthreads();
    constexpr int RPP = 256 / M;
    constexpr int RPB = 2048 / M;
    int m = threadIdx.x % M;
    int rend = (blockIdx.x + 1) * RPB; if (rend > nrows) rend = nrows;
    for (int r = blockIdx.x * RPB + threadIdx.x / M; r < rend; r += RPP) {
        const float* xr = X + (long long)r * K;
        float acc = 0.0f;
#pragma unroll 8
        for (int k = 0; k < K; ++k) acc = fmaf(xr[k], Wl[k * M + m], acc);
        if (SCALE) acc *= rowscale[r];
        out[(long long)r * M + m] = acc;
    }
}

// ---- GCN gather (pure row-sum of pre-scaled y): h = b + dt*(y[t] + sum y[s])
// D=128: 2 edges/wave (32 lanes x float4 each)
__global__ __launch_bounds__(256) void gcn_gather128_kernel(const float* __restrict__ y,
                                                            const float* __restrict__ dinv,
                                                            const int* __restrict__ off,
                                                            const int* __restrict__ srcs,
                                                            const float* __restrict__ b,
                                                            float* __restrict__ h, int n) {
    int node = blockIdx.x * 4 + (threadIdx.x >> 6);
    if (node >= n) return;
    int lane = threadIdx.x & 63;
    int sub = lane >> 5;       // 0..1
    int q = lane & 31;         // column quad
    int e0 = off[node], e1 = off[node + 1];
    float4 acc = make_float4(0.f, 0.f, 0.f, 0.f);
    int e = e0 + sub;
    int s = (e < e1) ? srcs[e] : 0;
    for (; e < e1; e += 2) {
        int sn = (e + 2 < e1) ? srcs[e + 2] : 0;
        const float4 v = *(const float4*)(y + (long long)s * 128 + q * 4);
        acc.x += v.x; acc.y += v.y; acc.z += v.z; acc.w += v.w;
        s = sn;
    }
    acc.x += __shfl_xor(acc.x, 32, 64);
    acc.y += __shfl_xor(acc.y, 32, 64);
    acc.z += __shfl_xor(acc.z, 32, 64);
    acc.w += __shfl_xor(acc.w, 32, 64);
    if (sub == 0) {
        float dt = dinv[node];
        const float4 ys = *(const float4*)(y + (long long)node * 128 + q * 4);
        const float4 bb = *(const float4*)(b + q * 4);
        float4 o;
        o.x = fmaf(dt, acc.x + ys.x, bb.x);
        o.y = fmaf(dt, acc.y + ys.y, bb.y);
        o.z = fmaf(dt, acc.z + ys.z, bb.z);
        o.w = fmaf(dt, acc.w + ys.w, bb.w);
        *(float4*)(h + (long long)node * 128 + q * 4) = o;
    }
}

// D=64: 4 edges/wave (16 lanes x float4 each)
__global__ __launch_bounds__(256) void gcn_gather64_kernel(const float* __restrict__ y,
                                                           const float* __restrict__ dinv,
                                                           const int* __restrict__ off,
                                                           const int* __restrict__ srcs,
                                                           const float* __restrict__ b,
                                                           float* __restrict__ h, int n) {
    int node = blockIdx.x * 4 + (threadIdx.x >> 6);
    if (node >= n) return;
    int lane = threadIdx.x & 63;
    int sub = lane >> 4;       // 0..3
    int q = lane & 15;
    int e0 = off[node], e1 = off[node + 1];
    float4 acc = make_float4(0.f, 0.f, 0.f, 0.f);
    int e = e0 + sub;
    int s = (e < e1) ? srcs[e] : 0;
    for (; e < e1; e += 4) {
        int sn = (e + 4 < e1) ? srcs[e + 4] : 0;
        const float4 v = *(const float4*)(y + (long long)s * 64 + q * 4);
        acc.x += v.x; acc.y += v.y; acc.z += v.z; acc.w += v.w;
        s = sn;
    }
    acc.x += __shfl_xor(acc.x, 16, 64); acc.x += __shfl_xor(acc.x, 32, 64);
    acc.y += __shfl_xor(acc.y, 16, 64); acc.y += __shfl_xor(acc.y, 32, 64);
    acc.z += __shfl_xor(acc.z, 16, 64); acc.z += __shfl_xor(acc.z, 32, 64);
    acc.w += __shfl_xor(acc.w, 16, 64); acc.w += __shfl_xor(acc.w, 32, 64);
    if (sub == 0) {
        float dt = dinv[node];
        const float4 ys = *(const float4*)(y + (long long)node * 64 + q * 4);
        const float4 bb = *(const float4*)(b + q * 4);
        float4 o;
        o.x = fmaf(dt, acc.x + ys.x, bb.x);
        o.y = fmaf(dt, acc.y + ys.y, bb.y);
        o.z = fmaf(dt, acc.z + ys.z, bb.z);
        o.w = fmaf(dt, acc.w + ys.w, bb.w);
        *(float4*)(h + (long long)node * 64 + q * 4) = o;
    }
}

// ---- HGNN gather: out[t] = sum_e val_e * in[idx_e]  (D=64, 4 edges/wave) ---
__global__ __launch_bounds__(256) void hg_gather_kernel(const float* __restrict__ in,
                                                        const int* __restrict__ off,
                                                        const int2* __restrict__ ents,
                                                        float* __restrict__ out, int n) {
    int node = blockIdx.x * 4 + (threadIdx.x >> 6);
    if (node >= n) return;
    int lane = threadIdx.x & 63;
    int sub = lane >> 4;
    int q = lane & 15;
    int e0 = off[node], e1 = off[node + 1];
    float4 acc = make_float4(0.f, 0.f, 0.f, 0.f);
    int e = e0 + sub;
    int2 t = (e < e1) ? ents[e] : make_int2(0, 0);
    for (; e < e1; e += 4) {
        int2 tn = (e + 4 < e1) ? ents[e + 4] : make_int2(0, 0);
        float vv = __int_as_float(t.y);
        const float4 v = *(const float4*)(in + (long long)t.x * 64 + q * 4);
        acc.x = fmaf(vv, v.x, acc.x);
        acc.y = fmaf(vv, v.y, acc.y);
        acc.z = fmaf(vv, v.z, acc.z);
        acc.w = fmaf(vv, v.w, acc.w);
        t = tn;
    }
    acc.x += __shfl_xor(acc.x, 16, 64); acc.x += __shfl_xor(acc.x, 32, 64);
    acc.y += __shfl_xor(acc.y, 16, 64); acc.y += __shfl_xor(acc.y, 32, 64);
    acc.z += __shfl_xor(acc.z, 16, 64); acc.z += __shfl_xor(acc.z, 32, 64);
    acc.w += __shfl_xor(acc.w, 16, 64); acc.w += __shfl_xor(acc.w, 32, 64);
    if (sub == 0) *(float4*)(out + (long long)node * 64 + q * 4) = acc;
}

// ---- BatchNorm (batch stats over N) ----------------------------------------
__global__ __launch_bounds__(256) void bn_stats_kernel(const float* __restrict__ h2,
                                                       float* __restrict__ stats,
                                                       int nrows, int rpb) {
    int col = threadIdx.x & 63;
    int grp = threadIdx.x >> 6;
    int r0 = blockIdx.x * rpb;
    int r1 = r0 + rpb; if (r1 > nrows) r1 = nrows;
    float s = 0.0f, s2 = 0.0f;
    for (int r = r0 + grp; r < r1; r += 4) {
        float v = h2[(long long)r * 64 + col];
        s += v; s2 += v * v;
    }
    __shared__ float ls[4][64], ls2[4][64];
    ls[grp][col] = s; ls2[grp][col] = s2;
    __syncthreads();
    if (grp == 0) {
        s  = ls[0][col] + ls[1][col] + ls[2][col] + ls[3][col];
        s2 = ls2[0][col] + ls2[1][col] + ls2[2][col] + ls2[3][col];
        atomicAdd(&stats[col], s);
        atomicAdd(&stats[64 + col], s2);
    }
}

__global__ __launch_bounds__(256) void bn_apply_kernel(float* __restrict__ h2,
                                                       const float* __restrict__ stats,
                                                       const float* __restrict__ gamma,
                                                       const float* __restrict__ beta,
                                                       const float* __restrict__ hbias,
                                                       float* __restrict__ xrelu,
                                                       int total, float invN) {
    int idx = blockIdx.x * 256 + threadIdx.x;
    if (idx >= total) return;
    int col = idx & 63;
    float mu = stats[col] * invN;
    float var = stats[64 + col] * invN - mu * mu;
    float v = (h2[idx] - mu) * rsqrtf(var + 1e-5f) * gamma[col] + beta[col];
    h2[idx] = v;
    xrelu[idx] = fmaxf(v, 0.0f) + hbias[col];
}

// ---- fused tail: row softmax -> fc1 -> fusion gate --------------------------
__global__ __launch_bounds__(256) void tail_kernel(const float* __restrict__ x2,
                                                   const float* __restrict__ hidden,
                                                   const float* __restrict__ fc1_W,
                                                   const float* __restrict__ W1,
                                                   const float* __restrict__ b1,
                                                   const float* __restrict__ w2,
                                                   const float* __restrict__ b2,
                                                   float* __restrict__ out, int nrows) {
    __shared__ float Lfc[64 * 64];  // Lfc[k*64+d] = fc1_W[d*64+k]
    __shared__ float Lf1[64 * 64];  // Lf1[k*64+d] = fus_l1_W[d*64+k]
    for (int i = threadIdx.x; i < 4096; i += 256) {
        int k = i >> 6, d = i & 63;
        Lfc[i] = fc1_W[d * 64 + k];
        Lf1[i] = W1[d * 64 + k];
    }
    __syncthreads();
    int d = threadIdx.x & 63;
    int w = threadIdx.x >> 6;
    float b1d = b1[d], w2d = w2[d], b20 = b2[0];
    for (int row = blockIdx.x * 4 + w; row < nrows; row += gridDim.x * 4) {
        long long o = (long long)row * 64 + d;
        // softmax over the row
        float v = x2[o];
        float m = v;
        for (int dd = 32; dd; dd >>= 1) m = fmaxf(m, __shfl_xor(m, dd, 64));
        float e = expf(v - m);
        float s = e;
        for (int dd = 32; dd; dd >>= 1) s += __shfl_xor(s, dd, 64);
        float p = e / s;
        // fc1: subn_d = sum_k p_k * fc1_W[d][k]
        float sv = 0.0f;
#pragma unroll
        for (int k = 0; k < 64; ++k) sv = fmaf(__shfl(p, k, 64), Lfc[k * 64 + d], sv);
        // fusion gates
        float hv = hidden[o];
        float accH = b1d, accS = b1d;
#pragma unroll
        for (int k = 0; k < 64; ++k) {
            float lw = Lf1[k * 64 + d];
            accH = fmaf(__shfl(hv, k, 64), lw, accH);
            accS = fmaf(__shfl(sv, k, 64), lw, accS);
        }
        float gH = tanhf(accH) * w2d, gS = tanhf(accS) * w2d;
        for (int dd = 32; dd; dd >>= 1) {
            gH += __shfl_xor(gH, dd, 64);
            gS += __shfl_xor(gS, dd, 64);
        }
        gH += b20; gS += b20;
        float mx = fmaxf(gH, gS);
        float eH = expf(gH - mx), eS = expf(gS - mx);
        float inv = 1.0f / (eH + eS);
        out[o] = (eH * hv + eS * sv) * inv;
    }
}

// ---------------------------------------------------------------------------
extern "C" void kernel_launch(void* const* d_in, const int* in_sizes, int n_in,
                              void* d_out, int out_size, void* d_ws, size_t ws_size,
                              hipStream_t stream) {
    const float* emb       = (const float*)d_in[0];
    const float* W1        = (const float*)d_in[1];
    const float* b1        = (const float*)d_in[2];
    const float* W2        = (const float*)d_in[3];
    const float* b2        = (const float*)d_in[4];
    const float* gamma     = (const float*)d_in[5];
    const float* beta      = (const float*)d_in[6];
    const float* hgc1_bias = (const float*)d_in[7];
    const float* fc1_W     = (const float*)d_in[8];
    const float* fus_l1_W  = (const float*)d_in[9];
    const float* fus_l1_b  = (const float*)d_in[10];
    const float* fus_l2_W  = (const float*)d_in[11];
    const float* fus_l2_b  = (const float*)d_in[12];
    const float* hg_val    = (const float*)d_in[13];
    const int*   edge_index= (const int*)d_in[14];
    const int*   hg_row    = (const int*)d_in[15];
    const int*   hg_col    = (const int*)d_in[16];

    const int N   = in_sizes[0] / 64;
    const int E   = in_sizes[14] / 2;
    const int NNZ = in_sizes[13];
    const int* src = edge_index;
    const int* dst = edge_index + E;

    // workspace layout (4B units):
    // dinv N | buf1 128N | buf2 128N | stats 128 |
    // gcn_off N+2 | gcn_cur N | gcn_srcs E |
    // hgc_off N+2 | hgc_cur N | hgr_off N+2 | hgr_cur N |
    // hgc_ent 2*NNZ | hgr_ent 2*NNZ
    float* ws      = (float*)d_ws;
    float* dinv    = ws;
    float* buf1    = dinv + N;
    float* buf2    = buf1 + (size_t)128 * N;
    float* stats   = buf2 + (size_t)128 * N;
    int*   gcn_off = (int*)(stats + 128);
    int*   gcn_cur = gcn_off + (N + 2);
    int*   gcn_srcs= gcn_cur + N;
    int*   hgc_off = gcn_srcs + E;
    int*   hgc_cur = hgc_off + (N + 2);
    int*   hgr_off = hgc_cur + N;
    int*   hgr_cur = hgr_off + (N + 2);
    int2*  hgc_ent = (int2*)(hgr_cur + N);
    int2*  hgr_ent = hgc_ent + NNZ;

    float* xw1  = buf1;                      // N x 128  (dinv-scaled)
    float* h1   = buf2;                      // N x 128
    float* xw2  = buf1;                      // N x 64   (dinv-scaled; xw1 dead)
    float* h2   = buf1 + (size_t)64 * N;     // N x 64 -> hidden (lives to end)
    float* xre  = buf2;                      // N x 64   (h1 dead)
    float* eemb = buf2 + (size_t)64 * N;     // N x 64
    float* x2   = buf1;                      // N x 64   (xw2 dead)
    float* out  = (float*)d_out;

    const int GB = 256;

    // --- CSR builds ---
    hipMemsetAsync(stats, 0, 128 * sizeof(float), stream);
    hipMemsetAsync(gcn_cur, 0, N * sizeof(int), stream);
    hipMemsetAsync(hgc_cur, 0, N * sizeof(int), stream);
    hipMemsetAsync(hgr_cur, 0, N * sizeof(int), stream);

    int hmax = (E > NNZ) ? E : NNZ;
    hist_all_kernel<<<(hmax + GB - 1) / GB, GB, 0, stream>>>(dst, E, hg_row, hg_col, NNZ,
                                                             gcn_cur, hgr_cur, hgc_cur);
    scan3_kernel<<<3, 1024, 0, stream>>>(gcn_cur, gcn_off, hgc_cur, hgc_off,
                                         hgr_cur, hgr_off, dinv, N);
    place_gcn_kernel<<<(E + GB - 1) / GB, GB, 0, stream>>>(src, dst, gcn_cur, gcn_srcs, E);
    hg_place_kernel<<<(NNZ + GB - 1) / GB, GB, 0, stream>>>(hg_row, hg_col, hg_val,
                                                            hgc_cur, hgr_cur, hgc_ent, hgr_ent, NNZ);

    // --- GCN layer 1: xw1 = (emb @ W1) * dinv[row]; gather-sum ---
    gemm_kernel<64, 128, true><<<(N + 15) / 16, 256, 0, stream>>>(emb, W1, dinv, xw1, N);
    gcn_gather128_kernel<<<(N + 3) / 4, 256, 0, stream>>>(xw1, dinv, gcn_off, gcn_srcs, b1, h1, N);

    // --- GCN layer 2 ---
    gemm_kernel<128, 64, true><<<(N + 31) / 32, 256, 0, stream>>>(h1, W2, dinv, xw2, N);
    gcn_gather64_kernel<<<(N + 3) / 4, 256, 0, stream>>>(xw2, dinv, gcn_off, gcn_srcs, b2, h2, N);

    // --- BatchNorm + relu + hgc1_bias ---
    {
        int nblocks = 256;
        int rpb = (N + nblocks - 1) / nblocks;
        bn_stats_kernel<<<nblocks, 256, 0, stream>>>(h2, stats, N, rpb);
        int total = N * 64;
        bn_apply_kernel<<<(total + 255) / 256, 256, 0, stream>>>(h2, stats, gamma, beta,
                                                                 hgc1_bias, xre, total, 1.0f / N);
    }

    // --- HGNN: edge_emb = G^T x ; x2 = G edge_emb ---
    hg_gather_kernel<<<(N + 3) / 4, 256, 0, stream>>>(xre, hgc_off, hgc_ent, eemb, N);
    hg_gather_kernel<<<(N + 3) / 4, 256, 0, stream>>>(eemb, hgr_off, hgr_ent, x2, N);

    // --- fused softmax + fc1 + fusion gate ---
    tail_kernel<<<1024, 256, 0, stream>>>(x2, h2, fc1_W, fus_l1_W, fus_l1_b,
                                          fus_l2_W, fus_l2_b, out, N);
}

// Round 4
// 808.421 us; speedup vs baseline: 3.9792x; 1.1365x over previous
//
#include <hip/hip_runtime.h>
#include <hip/hip_fp16.h>

// ---------------------------------------------------------------------------
// MSHGAT forward, round 4:
//  - tail (softmax+fc1+fusion) rewritten as register-tiled LDS GEMM
//    (64-row tiles, 4x4 register blocking) -- replaces shfl-matvec
//  - hg CSR entries packed to 4B (u16 idx | fp16 val): halves placement
//    write amplification and gather entry stream
//  - placement kernels merged
// N=50000, D=64, E=600000, NNZ=800000.
// ---------------------------------------------------------------------------

// ---- histograms (gcn by dst, hg by row and by col) -------------------------
__global__ __launch_bounds__(256) void hist_all_kernel(const int* __restrict__ dst, int e,
                                                       const int* __restrict__ row,
                                                       const int* __restrict__ col, int nnz,
                                                       int* __restrict__ cg,
                                                       int* __restrict__ cr,
                                                       int* __restrict__ cc) {
    int i = blockIdx.x * 256 + threadIdx.x;
    if (i < e) atomicAdd(&cg[dst[i]], 1);
    if (i < nnz) {
        atomicAdd(&cr[row[i]], 1);
        atomicAdd(&cc[col[i]], 1);
    }
}

// ---- 3 independent exclusive scans (block b -> array b) --------------------
__global__ __launch_bounds__(1024) void scan3_kernel(int* __restrict__ g_cnt, int* __restrict__ g_off,
                                                     int* __restrict__ c_cnt, int* __restrict__ c_off,
                                                     int* __restrict__ r_cnt, int* __restrict__ r_off,
                                                     float* __restrict__ dinv, int n) {
    int which = blockIdx.x;
    int* cnt = (which == 0) ? g_cnt : (which == 1) ? c_cnt : r_cnt;
    int* off = (which == 0) ? g_off : (which == 1) ? c_off : r_off;
    __shared__ int part[1024];
    int tid = threadIdx.x;
    int chunk = (n + 1023) / 1024;
    int s0 = tid * chunk, s1 = s0 + chunk;
    if (s1 > n) s1 = n;
    int sum = 0;
    for (int i = s0; i < s1; ++i) {
        int c = cnt[i];
        sum += c;
        if (which == 0) dinv[i] = rsqrtf((float)(c + 1));
    }
    part[tid] = sum;
    __syncthreads();
    for (int d = 1; d < 1024; d <<= 1) {
        int v = (tid >= d) ? part[tid - d] : 0;
        __syncthreads();
        part[tid] += v;
        __syncthreads();
    }
    int run = (tid == 0) ? 0 : part[tid - 1];
    for (int i = s0; i < s1; ++i) {
        int c = cnt[i];
        off[i] = run;
        cnt[i] = run;   // becomes "cur" for placement
        run += c;
    }
    if (tid == 1023) off[n] = part[1023];
}

// ---- placement (gcn srcs + packed hg entries, one launch) ------------------
__global__ __launch_bounds__(256) void place_all_kernel(const int* __restrict__ src,
                                                        const int* __restrict__ dst,
                                                        int* __restrict__ gcur,
                                                        int* __restrict__ gsrcs, int e,
                                                        const int* __restrict__ row,
                                                        const int* __restrict__ col,
                                                        const float* __restrict__ val,
                                                        int* __restrict__ curc,
                                                        int* __restrict__ curr,
                                                        unsigned* __restrict__ entc,
                                                        unsigned* __restrict__ entr, int nnz) {
    int i = blockIdx.x * 256 + threadIdx.x;
    if (i < e) {
        int pos = atomicAdd(&gcur[dst[i]], 1);
        gsrcs[pos] = src[i];
    }
    if (i < nnz) {
        int r = row[i], c = col[i];
        unsigned hv = (unsigned)__half_as_ushort(__float2half(val[i]));
        int pc = atomicAdd(&curc[c], 1);
        entc[pc] = ((unsigned)r << 16) | hv;    // CSR by col: (row, val)
        int pr = atomicAdd(&curr[r], 1);
        entr[pr] = ((unsigned)c << 16) | hv;    // CSR by row: (col, val)
    }
}

// ---- small dense GEMM: out[N,M] = X[N,K] @ W, optional per-row scale -------
template <int K, int M, bool SCALE>
__global__ __launch_bounds__(256) void gemm_kernel(const float* __restrict__ X,
                                                   const float* __restrict__ W,
                                                   const float* __restrict__ rowscale,
                                                   float* __restrict__ out, int nrows) {
    __shared__ float Wl[K * M];
    for (int i = threadIdx.x; i < K * M; i += 256) Wl[i] = W[i];
    __syncthreads();
    constexpr int RPP = 256 / M;
    constexpr int RPB = 2048 / M;
    int m = threadIdx.x % M;
    int rend = (blockIdx.x + 1) * RPB; if (rend > nrows) rend = nrows;
    for (int r = blockIdx.x * RPB + threadIdx.x / M; r < rend; r += RPP) {
        const float* xr = X + (long long)r * K;
        float acc = 0.0f;
#pragma unroll 8
        for (int k = 0; k < K; ++k) acc = fmaf(xr[k], Wl[k * M + m], acc);
        if (SCALE) acc *= rowscale[r];
        out[(long long)r * M + m] = acc;
    }
}

// ---- GCN gather (pure row-sum of pre-scaled y): h = b + dt*(y[t] + sum y[s])
__global__ __launch_bounds__(256) void gcn_gather128_kernel(const float* __restrict__ y,
                                                            const float* __restrict__ dinv,
                                                            const int* __restrict__ off,
                                                            const int* __restrict__ srcs,
                                                            const float* __restrict__ b,
                                                            float* __restrict__ h, int n) {
    int node = blockIdx.x * 4 + (threadIdx.x >> 6);
    if (node >= n) return;
    int lane = threadIdx.x & 63;
    int sub = lane >> 5;
    int q = lane & 31;
    int e0 = off[node], e1 = off[node + 1];
    float4 acc = make_float4(0.f, 0.f, 0.f, 0.f);
    int e = e0 + sub;
    int s = (e < e1) ? srcs[e] : 0;
    for (; e < e1; e += 2) {
        int sn = (e + 2 < e1) ? srcs[e + 2] : 0;
        const float4 v = *(const float4*)(y + (long long)s * 128 + q * 4);
        acc.x += v.x; acc.y += v.y; acc.z += v.z; acc.w += v.w;
        s = sn;
    }
    acc.x += __shfl_xor(acc.x, 32, 64);
    acc.y += __shfl_xor(acc.y, 32, 64);
    acc.z += __shfl_xor(acc.z, 32, 64);
    acc.w += __shfl_xor(acc.w, 32, 64);
    if (sub == 0) {
        float dt = dinv[node];
        const float4 ys = *(const float4*)(y + (long long)node * 128 + q * 4);
        const float4 bb = *(const float4*)(b + q * 4);
        float4 o;
        o.x = fmaf(dt, acc.x + ys.x, bb.x);
        o.y = fmaf(dt, acc.y + ys.y, bb.y);
        o.z = fmaf(dt, acc.z + ys.z, bb.z);
        o.w = fmaf(dt, acc.w + ys.w, bb.w);
        *(float4*)(h + (long long)node * 128 + q * 4) = o;
    }
}

__global__ __launch_bounds__(256) void gcn_gather64_kernel(const float* __restrict__ y,
                                                           const float* __restrict__ dinv,
                                                           const int* __restrict__ off,
                                                           const int* __restrict__ srcs,
                                                           const float* __restrict__ b,
                                                           float* __restrict__ h, int n) {
    int node = blockIdx.x * 4 + (threadIdx.x >> 6);
    if (node >= n) return;
    int lane = threadIdx.x & 63;
    int sub = lane >> 4;
    int q = lane & 15;
    int e0 = off[node], e1 = off[node + 1];
    float4 acc = make_float4(0.f, 0.f, 0.f, 0.f);
    int e = e0 + sub;
    int s = (e < e1) ? srcs[e] : 0;
    for (; e < e1; e += 4) {
        int sn = (e + 4 < e1) ? srcs[e + 4] : 0;
        const float4 v = *(const float4*)(y + (long long)s * 64 + q * 4);
        acc.x += v.x; acc.y += v.y; acc.z += v.z; acc.w += v.w;
        s = sn;
    }
    acc.x += __shfl_xor(acc.x, 16, 64); acc.x += __shfl_xor(acc.x, 32, 64);
    acc.y += __shfl_xor(acc.y, 16, 64); acc.y += __shfl_xor(acc.y, 32, 64);
    acc.z += __shfl_xor(acc.z, 16, 64); acc.z += __shfl_xor(acc.z, 32, 64);
    acc.w += __shfl_xor(acc.w, 16, 64); acc.w += __shfl_xor(acc.w, 32, 64);
    if (sub == 0) {
        float dt = dinv[node];
        const float4 ys = *(const float4*)(y + (long long)node * 64 + q * 4);
        const float4 bb = *(const float4*)(b + q * 4);
        float4 o;
        o.x = fmaf(dt, acc.x + ys.x, bb.x);
        o.y = fmaf(dt, acc.y + ys.y, bb.y);
        o.z = fmaf(dt, acc.z + ys.z, bb.z);
        o.w = fmaf(dt, acc.w + ys.w, bb.w);
        *(float4*)(h + (long long)node * 64 + q * 4) = o;
    }
}

// ---- HGNN gather with packed entries: out[t] = sum val_e * in[idx_e] -------
__global__ __launch_bounds__(256) void hg_gather_kernel(const float* __restrict__ in,
                                                        const int* __restrict__ off,
                                                        const unsigned* __restrict__ ents,
                                                        float* __restrict__ out, int n) {
    int node = blockIdx.x * 4 + (threadIdx.x >> 6);
    if (node >= n) return;
    int lane = threadIdx.x & 63;
    int sub = lane >> 4;
    int q = lane & 15;
    int e0 = off[node], e1 = off[node + 1];
    float4 acc = make_float4(0.f, 0.f, 0.f, 0.f);
    int e = e0 + sub;
    unsigned t = (e < e1) ? ents[e] : 0u;
    for (; e < e1; e += 4) {
        unsigned tn = (e + 4 < e1) ? ents[e + 4] : 0u;
        float vv = __half2float(__ushort_as_half((unsigned short)(t & 0xffffu)));
        const float4 v = *(const float4*)(in + (long long)(t >> 16) * 64 + q * 4);
        acc.x = fmaf(vv, v.x, acc.x);
        acc.y = fmaf(vv, v.y, acc.y);
        acc.z = fmaf(vv, v.z, acc.z);
        acc.w = fmaf(vv, v.w, acc.w);
        t = tn;
    }
    acc.x += __shfl_xor(acc.x, 16, 64); acc.x += __shfl_xor(acc.x, 32, 64);
    acc.y += __shfl_xor(acc.y, 16, 64); acc.y += __shfl_xor(acc.y, 32, 64);
    acc.z += __shfl_xor(acc.z, 16, 64); acc.z += __shfl_xor(acc.z, 32, 64);
    acc.w += __shfl_xor(acc.w, 16, 64); acc.w += __shfl_xor(acc.w, 32, 64);
    if (sub == 0) *(float4*)(out + (long long)node * 64 + q * 4) = acc;
}

// ---- BatchNorm ---------------------------------------------------------------
__global__ __launch_bounds__(256) void bn_stats_kernel(const float* __restrict__ h2,
                                                       float* __restrict__ stats,
                                                       int nrows, int rpb) {
    int col = threadIdx.x & 63;
    int grp = threadIdx.x >> 6;
    int r0 = blockIdx.x * rpb;
    int r1 = r0 + rpb; if (r1 > nrows) r1 = nrows;
    float s = 0.0f, s2 = 0.0f;
    for (int r = r0 + grp; r < r1; r += 4) {
        float v = h2[(long long)r * 64 + col];
        s += v; s2 += v * v;
    }
    __shared__ float ls[4][64], ls2[4][64];
    ls[grp][col] = s; ls2[grp][col] = s2;
    __syncthreads();
    if (grp == 0) {
        s  = ls[0][col] + ls[1][col] + ls[2][col] + ls[3][col];
        s2 = ls2[0][col] + ls2[1][col] + ls2[2][col] + ls2[3][col];
        atomicAdd(&stats[col], s);
        atomicAdd(&stats[64 + col], s2);
    }
}

__global__ __launch_bounds__(256) void bn_apply_kernel(float* __restrict__ h2,
                                                       const float* __restrict__ stats,
                                                       const float* __restrict__ gamma,
                                                       const float* __restrict__ beta,
                                                       const float* __restrict__ hbias,
                                                       float* __restrict__ xrelu,
                                                       int total, float invN) {
    int idx = blockIdx.x * 256 + threadIdx.x;
    if (idx >= total) return;
    int col = idx & 63;
    float mu = stats[col] * invN;
    float var = stats[64 + col] * invN - mu * mu;
    float v = (h2[idx] - mu) * rsqrtf(var + 1e-5f) * gamma[col] + beta[col];
    h2[idx] = v;
    xrelu[idx] = fmaxf(v, 0.0f) + hbias[col];
}

// ---- fused tail: softmax -> fc1 -> fusion gate, register-tiled LDS GEMM ----
// Block: 256 threads = (tx 0..15) x (ty 0..15). Tile: 64 rows.
// Thread owns rows r=4*ty+ri (ri 0..3), cols d=tx+16*di (di 0..3).
#define TPAD 68
__device__ __forceinline__ float dot4(float4 a, float4 b) {
    return fmaf(a.x, b.x, fmaf(a.y, b.y, fmaf(a.z, b.z, a.w * b.w)));
}

__global__ __launch_bounds__(256) void tail_kernel(const float* __restrict__ x2,
                                                   const float* __restrict__ hidden,
                                                   const float* __restrict__ fc1_W,
                                                   const float* __restrict__ fusW1,
                                                   const float* __restrict__ b1,
                                                   const float* __restrict__ w2,
                                                   const float* __restrict__ b2,
                                                   float* __restrict__ out, int n) {
    __shared__ float A[64 * TPAD];    // P (softmax probs), later S (subn)
    __shared__ float Hs[64 * TPAD];   // hidden tile
    __shared__ float WL[64 * TPAD];   // fc1_W, later fus_l1_W (row-major [d][k])
    int t = threadIdx.x;
    int tx = t & 15, ty = t >> 4;
    int r0 = blockIdx.x * 64;

    float b1d[4], w2d[4];
#pragma unroll
    for (int di = 0; di < 4; ++di) {
        b1d[di] = b1[tx + 16 * di];
        w2d[di] = w2[tx + 16 * di];
    }
    float b20 = b2[0];

    // weights fc1 -> WL ; hidden tile -> Hs (coalesced float4 copies)
    for (int f = t; f < 1024; f += 256) {
        int d = f >> 4, k4 = (f & 15) << 2;
        *(float4*)&WL[d * TPAD + k4] = *(const float4*)&fc1_W[d * 64 + k4];
        int gr = r0 + d;
        float4 hv = make_float4(0.f, 0.f, 0.f, 0.f);
        if (gr < n) hv = *(const float4*)&hidden[(long long)gr * 64 + k4];
        *(float4*)&Hs[d * TPAD + k4] = hv;
    }

    // x2 tile: load + row softmax -> A
#pragma unroll
    for (int ri = 0; ri < 4; ++ri) {
        int rl = 4 * ty + ri;
        int r = r0 + rl;
        bool ok = r < n;
        float vv[4];
#pragma unroll
        for (int di = 0; di < 4; ++di)
            vv[di] = ok ? x2[(long long)r * 64 + tx + 16 * di] : 0.f;
        float m = fmaxf(fmaxf(vv[0], vv[1]), fmaxf(vv[2], vv[3]));
        for (int s = 1; s < 16; s <<= 1) m = fmaxf(m, __shfl_xor(m, s, 16));
        float e0 = expf(vv[0] - m), e1 = expf(vv[1] - m);
        float e2 = expf(vv[2] - m), e3 = expf(vv[3] - m);
        float sm = e0 + e1 + e2 + e3;
        for (int s = 1; s < 16; s <<= 1) sm += __shfl_xor(sm, s, 16);
        float inv = 1.0f / sm;
        A[rl * TPAD + tx]      = e0 * inv;
        A[rl * TPAD + tx + 16] = e1 * inv;
        A[rl * TPAD + tx + 32] = e2 * inv;
        A[rl * TPAD + tx + 48] = e3 * inv;
    }
    __syncthreads();

    // fc1: sn[ri][di] = sum_k P[r][k] * fc1_W[d][k]
    float sn[4][4];
#pragma unroll
    for (int ri = 0; ri < 4; ++ri)
#pragma unroll
        for (int di = 0; di < 4; ++di) sn[ri][di] = 0.f;
    for (int k = 0; k < 64; k += 4) {
        float4 p4[4], w4[4];
#pragma unroll
        for (int ri = 0; ri < 4; ++ri) p4[ri] = *(float4*)&A[(4 * ty + ri) * TPAD + k];
#pragma unroll
        for (int di = 0; di < 4; ++di) w4[di] = *(float4*)&WL[(tx + 16 * di) * TPAD + k];
#pragma unroll
        for (int ri = 0; ri < 4; ++ri)
#pragma unroll
            for (int di = 0; di < 4; ++di)
                sn[ri][di] += dot4(p4[ri], w4[di]);
    }
    __syncthreads();   // P and fc1 weights fully consumed

    // S (subn) -> A ; fus_l1_W -> WL
#pragma unroll
    for (int ri = 0; ri < 4; ++ri)
#pragma unroll
        for (int di = 0; di < 4; ++di)
            A[(4 * ty + ri) * TPAD + tx + 16 * di] = sn[ri][di];
    for (int f = t; f < 1024; f += 256) {
        int d = f >> 4, k4 = (f & 15) << 2;
        *(float4*)&WL[d * TPAD + k4] = *(const float4*)&fusW1[d * 64 + k4];
    }
    __syncthreads();

    // gates: aH = H @ W1^T + b1 ; aS = S @ W1^T + b1
    float aH[4][4], aS[4][4];
#pragma unroll
    for (int ri = 0; ri < 4; ++ri)
#pragma unroll
        for (int di = 0; di < 4; ++di) { aH[ri][di] = b1d[di]; aS[ri][di] = b1d[di]; }
    for (int k = 0; k < 64; k += 4) {
        float4 h4[4], s4[4], w4[4];
#pragma unroll
        for (int ri = 0; ri < 4; ++ri) {
            h4[ri] = *(float4*)&Hs[(4 * ty + ri) * TPAD + k];
            s4[ri] = *(float4*)&A[(4 * ty + ri) * TPAD + k];
        }
#pragma unroll
        for (int di = 0; di < 4; ++di) w4[di] = *(float4*)&WL[(tx + 16 * di) * TPAD + k];
#pragma unroll
        for (int ri = 0; ri < 4; ++ri)
#pragma unroll
            for (int di = 0; di < 4; ++di) {
                aH[ri][di] += dot4(h4[ri], w4[di]);
                aS[ri][di] += dot4(s4[ri], w4[di]);
            }
    }

    // per-row: scores, softmax over 2 branches, combine, store
#pragma unroll
    for (int ri = 0; ri < 4; ++ri) {
        int rl = 4 * ty + ri;
        int r = r0 + rl;
        float pH = 0.f, pS = 0.f;
#pragma unroll
        for (int di = 0; di < 4; ++di) {
            pH = fmaf(tanhf(aH[ri][di]), w2d[di], pH);
            pS = fmaf(tanhf(aS[ri][di]), w2d[di], pS);
        }
        for (int s = 1; s < 16; s <<= 1) {
            pH += __shfl_xor(pH, s, 16);
            pS += __shfl_xor(pS, s, 16);
        }
        pH += b20; pS += b20;
        float mx = fmaxf(pH, pS);
        float eH = expf(pH - mx), eS = expf(pS - mx);
        float inv = 1.0f / (eH + eS);
        if (r < n) {
#pragma unroll
            for (int di = 0; di < 4; ++di) {
                int d = tx + 16 * di;
                float hv = Hs[rl * TPAD + d];
                out[(long long)r * 64 + d] = (eH * hv + eS * sn[ri][di]) * inv;
            }
        }
    }
}

// ---------------------------------------------------------------------------
extern "C" void kernel_launch(void* const* d_in, const int* in_sizes, int n_in,
                              void* d_out, int out_size, void* d_ws, size_t ws_size,
                              hipStream_t stream) {
    const float* emb       = (const float*)d_in[0];
    const float* W1        = (const float*)d_in[1];
    const float* b1        = (const float*)d_in[2];
    const float* W2        = (const float*)d_in[3];
    const float* b2        = (const float*)d_in[4];
    const float* gamma     = (const float*)d_in[5];
    const float* beta      = (const float*)d_in[6];
    const float* hgc1_bias = (const float*)d_in[7];
    const float* fc1_W     = (const float*)d_in[8];
    const float* fus_l1_W  = (const float*)d_in[9];
    const float* fus_l1_b  = (const float*)d_in[10];
    const float* fus_l2_W  = (const float*)d_in[11];
    const float* fus_l2_b  = (const float*)d_in[12];
    const float* hg_val    = (const float*)d_in[13];
    const int*   edge_index= (const int*)d_in[14];
    const int*   hg_row    = (const int*)d_in[15];
    const int*   hg_col    = (const int*)d_in[16];

    const int N   = in_sizes[0] / 64;
    const int E   = in_sizes[14] / 2;
    const int NNZ = in_sizes[13];
    const int* src = edge_index;
    const int* dst = edge_index + E;

    // workspace layout (4B units):
    // dinv N | buf1 128N | buf2 128N | stats 128 |
    // gcn_off N+2 | gcn_cur N | gcn_srcs E |
    // hgc_off N+2 | hgc_cur N | hgr_off N+2 | hgr_cur N |
    // hgc_ent NNZ | hgr_ent NNZ   (packed u16 idx | fp16 val)
    float* ws      = (float*)d_ws;
    float* dinv    = ws;
    float* buf1    = dinv + N;
    float* buf2    = buf1 + (size_t)128 * N;
    float* stats   = buf2 + (size_t)128 * N;
    int*   gcn_off = (int*)(stats + 128);
    int*   gcn_cur = gcn_off + (N + 2);
    int*   gcn_srcs= gcn_cur + N;
    int*   hgc_off = gcn_srcs + E;
    int*   hgc_cur = hgc_off + (N + 2);
    int*   hgr_off = hgc_cur + N;
    int*   hgr_cur = hgr_off + (N + 2);
    unsigned* hgc_ent = (unsigned*)(hgr_cur + N);
    unsigned* hgr_ent = hgc_ent + NNZ;

    float* xw1  = buf1;                      // N x 128  (dinv-scaled)
    float* h1   = buf2;                      // N x 128
    float* xw2  = buf1;                      // N x 64   (xw1 dead)
    float* h2   = buf1 + (size_t)64 * N;     // N x 64 -> hidden (lives to end)
    float* xre  = buf2;                      // N x 64   (h1 dead)
    float* eemb = buf2 + (size_t)64 * N;     // N x 64
    float* x2   = buf1;                      // N x 64   (xw2 dead)
    float* out  = (float*)d_out;

    const int GB = 256;

    // --- CSR builds ---
    hipMemsetAsync(stats, 0, 128 * sizeof(float), stream);
    hipMemsetAsync(gcn_cur, 0, N * sizeof(int), stream);
    hipMemsetAsync(hgc_cur, 0, N * sizeof(int), stream);
    hipMemsetAsync(hgr_cur, 0, N * sizeof(int), stream);

    int hmax = (E > NNZ) ? E : NNZ;
    hist_all_kernel<<<(hmax + GB - 1) / GB, GB, 0, stream>>>(dst, E, hg_row, hg_col, NNZ,
                                                             gcn_cur, hgr_cur, hgc_cur);
    scan3_kernel<<<3, 1024, 0, stream>>>(gcn_cur, gcn_off, hgc_cur, hgc_off,
                                         hgr_cur, hgr_off, dinv, N);
    place_all_kernel<<<(hmax + GB - 1) / GB, GB, 0, stream>>>(src, dst, gcn_cur, gcn_srcs, E,
                                                              hg_row, hg_col, hg_val,
                                                              hgc_cur, hgr_cur,
                                                              hgc_ent, hgr_ent, NNZ);

    // --- GCN layer 1: xw1 = (emb @ W1) * dinv[row]; gather-sum ---
    gemm_kernel<64, 128, true><<<(N + 15) / 16, 256, 0, stream>>>(emb, W1, dinv, xw1, N);
    gcn_gather128_kernel<<<(N + 3) / 4, 256, 0, stream>>>(xw1, dinv, gcn_off, gcn_srcs, b1, h1, N);

    // --- GCN layer 2 ---
    gemm_kernel<128, 64, true><<<(N + 31) / 32, 256, 0, stream>>>(h1, W2, dinv, xw2, N);
    gcn_gather64_kernel<<<(N + 3) / 4, 256, 0, stream>>>(xw2, dinv, gcn_off, gcn_srcs, b2, h2, N);

    // --- BatchNorm + relu + hgc1_bias ---
    {
        int nblocks = 256;
        int rpb = (N + nblocks - 1) / nblocks;
        bn_stats_kernel<<<nblocks, 256, 0, stream>>>(h2, stats, N, rpb);
        int total = N * 64;
        bn_apply_kernel<<<(total + 255) / 256, 256, 0, stream>>>(h2, stats, gamma, beta,
                                                                 hgc1_bias, xre, total, 1.0f / N);
    }

    // --- HGNN: edge_emb = G^T x ; x2 = G edge_emb ---
    hg_gather_kernel<<<(N + 3) / 4, 256, 0, stream>>>(xre, hgc_off, hgc_ent, eemb, N);
    hg_gather_kernel<<<(N + 3) / 4, 256, 0, stream>>>(eemb, hgr_off, hgr_ent, x2, N);

    // --- fused softmax + fc1 + fusion gate (tiled) ---
    tail_kernel<<<(N + 63) / 64, 256, 0, stream>>>(x2, h2, fc1_W, fus_l1_W, fus_l1_b,
                                                   fus_l2_W, fus_l2_b, out, N);
}

// Round 5
// 661.253 us; speedup vs baseline: 4.8648x; 1.2226x over previous
//
#include <hip/hip_runtime.h>
#include <hip/hip_fp16.h>

// ---------------------------------------------------------------------------
// MSHGAT forward, round 5:
//  - GCN reassociated: h2 = (A^2 X)(W1W2) + rowsum(A)*(b1W2) + b2
//    (aggregation commutes with right-multiply; both gathers now D=64 on X)
//  - BatchNorm fused into consumers (hg_gather#1 and tail); bn_apply dropped
//  - single memset (zeroed regions made contiguous)
// N=50000, D=64, E=600000, NNZ=800000.
// ---------------------------------------------------------------------------

// ---- histograms (gcn by dst, hg by row and by col) -------------------------
__global__ __launch_bounds__(256) void hist_all_kernel(const int* __restrict__ dst, int e,
                                                       const int* __restrict__ row,
                                                       const int* __restrict__ col, int nnz,
                                                       int* __restrict__ cg,
                                                       int* __restrict__ cr,
                                                       int* __restrict__ cc) {
    int i = blockIdx.x * 256 + threadIdx.x;
    if (i < e) atomicAdd(&cg[dst[i]], 1);
    if (i < nnz) {
        atomicAdd(&cr[row[i]], 1);
        atomicAdd(&cc[col[i]], 1);
    }
}

// ---- 3 independent exclusive scans (block b -> array b) --------------------
// Block 0 additionally writes dinv[i] = rsqrt(indeg + 1) from original counts.
__global__ __launch_bounds__(1024) void scan3_kernel(int* __restrict__ g_cnt, int* __restrict__ g_off,
                                                     int* __restrict__ c_cnt, int* __restrict__ c_off,
                                                     int* __restrict__ r_cnt, int* __restrict__ r_off,
                                                     float* __restrict__ dinv, int n) {
    int which = blockIdx.x;
    int* cnt = (which == 0) ? g_cnt : (which == 1) ? c_cnt : r_cnt;
    int* off = (which == 0) ? g_off : (which == 1) ? c_off : r_off;
    __shared__ int part[1024];
    int tid = threadIdx.x;
    int chunk = (n + 1023) / 1024;
    int s0 = tid * chunk, s1 = s0 + chunk;
    if (s1 > n) s1 = n;
    int sum = 0;
    for (int i = s0; i < s1; ++i) {
        int c = cnt[i];
        sum += c;
        if (which == 0) dinv[i] = rsqrtf((float)(c + 1));
    }
    part[tid] = sum;
    __syncthreads();
    for (int d = 1; d < 1024; d <<= 1) {
        int v = (tid >= d) ? part[tid - d] : 0;
        __syncthreads();
        part[tid] += v;
        __syncthreads();
    }
    int run = (tid == 0) ? 0 : part[tid - 1];
    for (int i = s0; i < s1; ++i) {
        int c = cnt[i];
        off[i] = run;
        cnt[i] = run;   // becomes "cur" for placement
        run += c;
    }
    if (tid == 1023) off[n] = part[1023];
}

// ---- placement (gcn srcs + packed hg entries) -------------------------------
__global__ __launch_bounds__(256) void place_all_kernel(const int* __restrict__ src,
                                                        const int* __restrict__ dst,
                                                        int* __restrict__ gcur,
                                                        int* __restrict__ gsrcs, int e,
                                                        const int* __restrict__ row,
                                                        const int* __restrict__ col,
                                                        const float* __restrict__ val,
                                                        int* __restrict__ curc,
                                                        int* __restrict__ curr,
                                                        unsigned* __restrict__ entc,
                                                        unsigned* __restrict__ entr, int nnz) {
    int i = blockIdx.x * 256 + threadIdx.x;
    if (i < e) {
        int pos = atomicAdd(&gcur[dst[i]], 1);
        gsrcs[pos] = src[i];
    }
    if (i < nnz) {
        int r = row[i], c = col[i];
        unsigned hv = (unsigned)__half_as_ushort(__float2half(val[i]));
        int pc = atomicAdd(&curc[c], 1);
        entc[pc] = ((unsigned)r << 16) | hv;    // CSR by col: (row, val)
        int pr = atomicAdd(&curr[r], 1);
        entr[pr] = ((unsigned)c << 16) | hv;    // CSR by row: (col, val)
    }
}

// ---- weight precompute: W12 = W1@W2 (64x64), bw = b1@W2 (64) ----------------
// grid 65 blocks x 64 threads; block r<64 -> W12 row r, block 64 -> bw.
__global__ __launch_bounds__(64) void wprep_kernel(const float* __restrict__ W1,  // 64x128
                                                   const float* __restrict__ W2,  // 128x64
                                                   const float* __restrict__ b1,  // 128
                                                   float* __restrict__ W12,
                                                   float* __restrict__ bw) {
    int r = blockIdx.x;
    int c = threadIdx.x;
    const float* a = (r < 64) ? (W1 + r * 128) : b1;
    float acc = 0.f;
#pragma unroll 8
    for (int k = 0; k < 128; ++k) acc = fmaf(a[k], W2[k * 64 + c], acc);
    if (r < 64) W12[r * 64 + c] = acc;
    else bw[c] = acc;
}

// ---- GCN gather (normalized):
// out_i = dinv_i * (dinv_i * x_i + sum_e dinv_s * x_s)
// SDI: also sdi_i = dinv_i * (dinv_i + sum_e dinv_s)  == rowsum(A-hat)_i
template <bool SDI>
__global__ __launch_bounds__(256) void gcn_gather_kernel(const float* __restrict__ x,
                                                         const float* __restrict__ dinv,
                                                         const int* __restrict__ off,
                                                         const int* __restrict__ srcs,
                                                         float* __restrict__ out,
                                                         float* __restrict__ sdi, int n) {
    int node = blockIdx.x * 4 + (threadIdx.x >> 6);
    if (node >= n) return;
    int lane = threadIdx.x & 63;
    int sub = lane >> 4;
    int q = lane & 15;
    int e0 = off[node], e1 = off[node + 1];
    float4 acc = make_float4(0.f, 0.f, 0.f, 0.f);
    float dsum = 0.f;
    int e = e0 + sub;
    int s = (e < e1) ? srcs[e] : 0;
    float ds = (e < e1) ? dinv[s] : 0.f;
    for (; e < e1; e += 4) {
        int sn = (e + 4 < e1) ? srcs[e + 4] : 0;
        float dsn = (e + 4 < e1) ? dinv[sn] : 0.f;
        const float4 v = *(const float4*)(x + (long long)s * 64 + q * 4);
        acc.x = fmaf(ds, v.x, acc.x);
        acc.y = fmaf(ds, v.y, acc.y);
        acc.z = fmaf(ds, v.z, acc.z);
        acc.w = fmaf(ds, v.w, acc.w);
        dsum += ds;
        s = sn; ds = dsn;
    }
    acc.x += __shfl_xor(acc.x, 16, 64); acc.x += __shfl_xor(acc.x, 32, 64);
    acc.y += __shfl_xor(acc.y, 16, 64); acc.y += __shfl_xor(acc.y, 32, 64);
    acc.z += __shfl_xor(acc.z, 16, 64); acc.z += __shfl_xor(acc.z, 32, 64);
    acc.w += __shfl_xor(acc.w, 16, 64); acc.w += __shfl_xor(acc.w, 32, 64);
    if (SDI) { dsum += __shfl_xor(dsum, 16, 64); dsum += __shfl_xor(dsum, 32, 64); }
    if (sub == 0) {
        float dt = dinv[node];
        const float4 xs = *(const float4*)(x + (long long)node * 64 + q * 4);
        float4 o;
        o.x = dt * fmaf(dt, xs.x, acc.x);
        o.y = dt * fmaf(dt, xs.y, acc.y);
        o.z = dt * fmaf(dt, xs.z, acc.z);
        o.w = dt * fmaf(dt, xs.w, acc.w);
        *(float4*)(out + (long long)node * 64 + q * 4) = o;
        if (SDI && q == 0) sdi[node] = dt * (dt + dsum);
    }
}

// ---- GEMM h2 = u @ W12 + sdi[r]*bw + b2 -------------------------------------
__global__ __launch_bounds__(256) void gemm_h2_kernel(const float* __restrict__ X,
                                                      const float* __restrict__ W12,
                                                      const float* __restrict__ bw,
                                                      const float* __restrict__ b2,
                                                      const float* __restrict__ sdi,
                                                      float* __restrict__ h2, int n) {
    __shared__ float Wl[64 * 64];
    __shared__ float cadd[64], b2l[64];
    for (int i = threadIdx.x; i < 4096; i += 256) Wl[i] = W12[i];
    if (threadIdx.x < 64) cadd[threadIdx.x] = bw[threadIdx.x];
    else if (threadIdx.x < 128) b2l[threadIdx.x - 64] = b2[threadIdx.x - 64];
    __syncthreads();
    int m = threadIdx.x & 63;
    int rend = (blockIdx.x + 1) * 32; if (rend > n) rend = n;
    for (int r = blockIdx.x * 32 + (threadIdx.x >> 6); r < rend; r += 4) {
        const float* xr = X + (long long)r * 64;
        float acc = 0.0f;
#pragma unroll 8
        for (int k = 0; k < 64; ++k) acc = fmaf(xr[k], Wl[k * 64 + m], acc);
        h2[(long long)r * 64 + m] = acc + sdi[r] * cadd[m] + b2l[m];
    }
}

// ---- BatchNorm stats (over raw h2) ------------------------------------------
__global__ __launch_bounds__(256) void bn_stats_kernel(const float* __restrict__ h2,
                                                       float* __restrict__ stats,
                                                       int nrows, int rpb) {
    int col = threadIdx.x & 63;
    int grp = threadIdx.x >> 6;
    int r0 = blockIdx.x * rpb;
    int r1 = r0 + rpb; if (r1 > nrows) r1 = nrows;
    float s = 0.0f, s2 = 0.0f;
    for (int r = r0 + grp; r < r1; r += 4) {
        float v = h2[(long long)r * 64 + col];
        s += v; s2 += v * v;
    }
    __shared__ float ls[4][64], ls2[4][64];
    ls[grp][col] = s; ls2[grp][col] = s2;
    __syncthreads();
    if (grp == 0) {
        s  = ls[0][col] + ls[1][col] + ls[2][col] + ls[3][col];
        s2 = ls2[0][col] + ls2[1][col] + ls2[2][col] + ls2[3][col];
        atomicAdd(&stats[col], s);
        atomicAdd(&stats[64 + col], s2);
    }
}

// ---- HGNN gather; BN=true applies bn+relu+hgc1_bias to gathered rows --------
template <bool BN>
__global__ __launch_bounds__(256) void hg_gather_kernel(const float* __restrict__ in,
                                                        const int* __restrict__ off,
                                                        const unsigned* __restrict__ ents,
                                                        const float* __restrict__ stats,
                                                        const float* __restrict__ gamma,
                                                        const float* __restrict__ beta,
                                                        const float* __restrict__ hbias,
                                                        float invN,
                                                        float* __restrict__ out, int n) {
    int node = blockIdx.x * 4 + (threadIdx.x >> 6);
    if (node >= n) return;
    int lane = threadIdx.x & 63;
    int sub = lane >> 4;
    int q = lane & 15;
    float sc[4], sh[4], hb[4];
    if (BN) {
#pragma unroll
        for (int c = 0; c < 4; ++c) {
            int col = q * 4 + c;
            float mu = stats[col] * invN;
            float var = stats[64 + col] * invN - mu * mu;
            float s = gamma[col] * rsqrtf(var + 1e-5f);
            sc[c] = s; sh[c] = beta[col] - mu * s; hb[c] = hbias[col];
        }
    }
    int e0 = off[node], e1 = off[node + 1];
    float4 acc = make_float4(0.f, 0.f, 0.f, 0.f);
    int e = e0 + sub;
    unsigned t = (e < e1) ? ents[e] : 0u;
    for (; e < e1; e += 4) {
        unsigned tn = (e + 4 < e1) ? ents[e + 4] : 0u;
        float vv = __half2float(__ushort_as_half((unsigned short)(t & 0xffffu)));
        float4 v = *(const float4*)(in + (long long)(t >> 16) * 64 + q * 4);
        if (BN) {
            v.x = fmaxf(fmaf(v.x, sc[0], sh[0]), 0.f) + hb[0];
            v.y = fmaxf(fmaf(v.y, sc[1], sh[1]), 0.f) + hb[1];
            v.z = fmaxf(fmaf(v.z, sc[2], sh[2]), 0.f) + hb[2];
            v.w = fmaxf(fmaf(v.w, sc[3], sh[3]), 0.f) + hb[3];
        }
        acc.x = fmaf(vv, v.x, acc.x);
        acc.y = fmaf(vv, v.y, acc.y);
        acc.z = fmaf(vv, v.z, acc.z);
        acc.w = fmaf(vv, v.w, acc.w);
        t = tn;
    }
    acc.x += __shfl_xor(acc.x, 16, 64); acc.x += __shfl_xor(acc.x, 32, 64);
    acc.y += __shfl_xor(acc.y, 16, 64); acc.y += __shfl_xor(acc.y, 32, 64);
    acc.z += __shfl_xor(acc.z, 16, 64); acc.z += __shfl_xor(acc.z, 32, 64);
    acc.w += __shfl_xor(acc.w, 16, 64); acc.w += __shfl_xor(acc.w, 32, 64);
    if (sub == 0) *(float4*)(out + (long long)node * 64 + q * 4) = acc;
}

// ---- fused tail: softmax -> fc1 -> fusion gate; bn applied to hidden --------
#define TPAD 68
__device__ __forceinline__ float dot4(float4 a, float4 b) {
    return fmaf(a.x, b.x, fmaf(a.y, b.y, fmaf(a.z, b.z, a.w * b.w)));
}

__global__ __launch_bounds__(256) void tail_kernel(const float* __restrict__ x2,
                                                   const float* __restrict__ h2raw,
                                                   const float* __restrict__ fc1_W,
                                                   const float* __restrict__ fusW1,
                                                   const float* __restrict__ b1,
                                                   const float* __restrict__ w2,
                                                   const float* __restrict__ b2,
                                                   const float* __restrict__ stats,
                                                   const float* __restrict__ gamma,
                                                   const float* __restrict__ beta,
                                                   float invN,
                                                   float* __restrict__ out, int n) {
    __shared__ float A[64 * TPAD];    // P (softmax probs), later S (subn)
    __shared__ float Hs[64 * TPAD];   // hidden tile (bn applied)
    __shared__ float WL[64 * TPAD];   // fc1_W, later fus_l1_W
    __shared__ float bsc[64], bsh[64];
    int t = threadIdx.x;
    int tx = t & 15, ty = t >> 4;
    int r0 = blockIdx.x * 64;

    if (t < 64) {
        float mu = stats[t] * invN;
        float var = stats[64 + t] * invN - mu * mu;
        float s = gamma[t] * rsqrtf(var + 1e-5f);
        bsc[t] = s; bsh[t] = beta[t] - mu * s;
    }
    __syncthreads();

    float b1d[4], w2d[4];
#pragma unroll
    for (int di = 0; di < 4; ++di) {
        b1d[di] = b1[tx + 16 * di];
        w2d[di] = w2[tx + 16 * di];
    }
    float b20 = b2[0];

    // fc1 weights -> WL ; bn(hidden) tile -> Hs
    for (int f = t; f < 1024; f += 256) {
        int d = f >> 4, k4 = (f & 15) << 2;
        *(float4*)&WL[d * TPAD + k4] = *(const float4*)&fc1_W[d * 64 + k4];
        int gr = r0 + d;
        float4 hv = make_float4(0.f, 0.f, 0.f, 0.f);
        if (gr < n) {
            hv = *(const float4*)&h2raw[(long long)gr * 64 + k4];
            hv.x = fmaf(hv.x, bsc[k4],     bsh[k4]);
            hv.y = fmaf(hv.y, bsc[k4 + 1], bsh[k4 + 1]);
            hv.z = fmaf(hv.z, bsc[k4 + 2], bsh[k4 + 2]);
            hv.w = fmaf(hv.w, bsc[k4 + 3], bsh[k4 + 3]);
        }
        *(float4*)&Hs[d * TPAD + k4] = hv;
    }

    // x2 tile: load + row softmax -> A
#pragma unroll
    for (int ri = 0; ri < 4; ++ri) {
        int rl = 4 * ty + ri;
        int r = r0 + rl;
        bool ok = r < n;
        float vv[4];
#pragma unroll
        for (int di = 0; di < 4; ++di)
            vv[di] = ok ? x2[(long long)r * 64 + tx + 16 * di] : 0.f;
        float m = fmaxf(fmaxf(vv[0], vv[1]), fmaxf(vv[2], vv[3]));
        for (int s = 1; s < 16; s <<= 1) m = fmaxf(m, __shfl_xor(m, s, 16));
        float e0 = expf(vv[0] - m), e1 = expf(vv[1] - m);
        float e2 = expf(vv[2] - m), e3 = expf(vv[3] - m);
        float sm = e0 + e1 + e2 + e3;
        for (int s = 1; s < 16; s <<= 1) sm += __shfl_xor(sm, s, 16);
        float inv = 1.0f / sm;
        A[rl * TPAD + tx]      = e0 * inv;
        A[rl * TPAD + tx + 16] = e1 * inv;
        A[rl * TPAD + tx + 32] = e2 * inv;
        A[rl * TPAD + tx + 48] = e3 * inv;
    }
    __syncthreads();

    // fc1: sn = P @ fc1_W^T
    float sn[4][4];
#pragma unroll
    for (int ri = 0; ri < 4; ++ri)
#pragma unroll
        for (int di = 0; di < 4; ++di) sn[ri][di] = 0.f;
    for (int k = 0; k < 64; k += 4) {
        float4 p4[4], w4[4];
#pragma unroll
        for (int ri = 0; ri < 4; ++ri) p4[ri] = *(float4*)&A[(4 * ty + ri) * TPAD + k];
#pragma unroll
        for (int di = 0; di < 4; ++di) w4[di] = *(float4*)&WL[(tx + 16 * di) * TPAD + k];
#pragma unroll
        for (int ri = 0; ri < 4; ++ri)
#pragma unroll
            for (int di = 0; di < 4; ++di)
                sn[ri][di] += dot4(p4[ri], w4[di]);
    }
    __syncthreads();

    // S (subn) -> A ; fus_l1_W -> WL
#pragma unroll
    for (int ri = 0; ri < 4; ++ri)
#pragma unroll
        for (int di = 0; di < 4; ++di)
            A[(4 * ty + ri) * TPAD + tx + 16 * di] = sn[ri][di];
    for (int f = t; f < 1024; f += 256) {
        int d = f >> 4, k4 = (f & 15) << 2;
        *(float4*)&WL[d * TPAD + k4] = *(const float4*)&fusW1[d * 64 + k4];
    }
    __syncthreads();

    // gates
    float aH[4][4], aS[4][4];
#pragma unroll
    for (int ri = 0; ri < 4; ++ri)
#pragma unroll
        for (int di = 0; di < 4; ++di) { aH[ri][di] = b1d[di]; aS[ri][di] = b1d[di]; }
    for (int k = 0; k < 64; k += 4) {
        float4 h4[4], s4[4], w4[4];
#pragma unroll
        for (int ri = 0; ri < 4; ++ri) {
            h4[ri] = *(float4*)&Hs[(4 * ty + ri) * TPAD + k];
            s4[ri] = *(float4*)&A[(4 * ty + ri) * TPAD + k];
        }
#pragma unroll
        for (int di = 0; di < 4; ++di) w4[di] = *(float4*)&WL[(tx + 16 * di) * TPAD + k];
#pragma unroll
        for (int ri = 0; ri < 4; ++ri)
#pragma unroll
            for (int di = 0; di < 4; ++di) {
                aH[ri][di] += dot4(h4[ri], w4[di]);
                aS[ri][di] += dot4(s4[ri], w4[di]);
            }
    }

#pragma unroll
    for (int ri = 0; ri < 4; ++ri) {
        int rl = 4 * ty + ri;
        int r = r0 + rl;
        float pH = 0.f, pS = 0.f;
#pragma unroll
        for (int di = 0; di < 4; ++di) {
            pH = fmaf(tanhf(aH[ri][di]), w2d[di], pH);
            pS = fmaf(tanhf(aS[ri][di]), w2d[di], pS);
        }
        for (int s = 1; s < 16; s <<= 1) {
            pH += __shfl_xor(pH, s, 16);
            pS += __shfl_xor(pS, s, 16);
        }
        pH += b20; pS += b20;
        float mx = fmaxf(pH, pS);
        float eH = expf(pH - mx), eS = expf(pS - mx);
        float inv = 1.0f / (eH + eS);
        if (r < n) {
#pragma unroll
            for (int di = 0; di < 4; ++di) {
                int d = tx + 16 * di;
                float hv = Hs[rl * TPAD + d];
                out[(long long)r * 64 + d] = (eH * hv + eS * sn[ri][di]) * inv;
            }
        }
    }
}

// ---------------------------------------------------------------------------
extern "C" void kernel_launch(void* const* d_in, const int* in_sizes, int n_in,
                              void* d_out, int out_size, void* d_ws, size_t ws_size,
                              hipStream_t stream) {
    const float* emb       = (const float*)d_in[0];
    const float* W1        = (const float*)d_in[1];
    const float* b1        = (const float*)d_in[2];
    const float* W2        = (const float*)d_in[3];
    const float* b2        = (const float*)d_in[4];
    const float* gamma     = (const float*)d_in[5];
    const float* beta      = (const float*)d_in[6];
    const float* hgc1_bias = (const float*)d_in[7];
    const float* fc1_W     = (const float*)d_in[8];
    const float* fus_l1_W  = (const float*)d_in[9];
    const float* fus_l1_b  = (const float*)d_in[10];
    const float* fus_l2_W  = (const float*)d_in[11];
    const float* fus_l2_b  = (const float*)d_in[12];
    const float* hg_val    = (const float*)d_in[13];
    const int*   edge_index= (const int*)d_in[14];
    const int*   hg_row    = (const int*)d_in[15];
    const int*   hg_col    = (const int*)d_in[16];

    const int N   = in_sizes[0] / 64;
    const int E   = in_sizes[14] / 2;
    const int NNZ = in_sizes[13];
    const int Np  = (N + 3) & ~3;           // 16B-aligned strides
    const int* src = edge_index;
    const int* dst = edge_index + E;

    // workspace layout (4B units, all offsets multiples of 4):
    // dinv Np | sdi Np | w12 4096 | bw 64 |
    // Z: [stats 128 | gcn_cnt Np | hgc_cnt Np | hgr_cnt Np]   <- single memset
    // gcn_off Np+4 | hgc_off Np+4 | hgr_off Np+4 |
    // gcn_srcs E | hgc_ent NNZ | hgr_ent NNZ | buf1 128*Np | buf2 64*Np
    float* ws      = (float*)d_ws;
    float* dinv    = ws;
    float* sdi     = dinv + Np;
    float* w12     = sdi + Np;
    float* bw      = w12 + 4096;
    float* stats   = bw + 64;
    int*   gcn_cnt = (int*)(stats + 128);
    int*   hgc_cnt = gcn_cnt + Np;
    int*   hgr_cnt = hgc_cnt + Np;
    int*   gcn_off = hgr_cnt + Np;
    int*   hgc_off = gcn_off + (Np + 4);
    int*   hgr_off = hgc_off + (Np + 4);
    int*   gcn_srcs= hgr_off + (Np + 4);
    unsigned* hgc_ent = (unsigned*)(gcn_srcs + E);
    unsigned* hgr_ent = hgc_ent + NNZ;
    float* buf1    = (float*)(hgr_ent + NNZ);
    float* buf2    = buf1 + (size_t)128 * Np;

    float* tbuf = buf2;                      // A-hat emb        N x 64
    float* ubuf = buf1;                      // A-hat^2 emb      N x 64
    float* h2   = buf1 + (size_t)64 * Np;    // raw h2 (pre-bn)  N x 64
    float* eemb = buf2;                      // edge emb         N x 64 (tbuf dead)
    float* x2   = buf1;                      // HGNN out         N x 64 (ubuf dead)
    float* out  = (float*)d_out;

    const int GB = 256;
    const float invN = 1.0f / (float)N;

    // --- CSR builds ---
    hipMemsetAsync(stats, 0, (size_t)(128 + 3 * Np) * sizeof(int), stream);
    int hmax = (E > NNZ) ? E : NNZ;
    hist_all_kernel<<<(hmax + GB - 1) / GB, GB, 0, stream>>>(dst, E, hg_row, hg_col, NNZ,
                                                             gcn_cnt, hgr_cnt, hgc_cnt);
    scan3_kernel<<<3, 1024, 0, stream>>>(gcn_cnt, gcn_off, hgc_cnt, hgc_off,
                                         hgr_cnt, hgr_off, dinv, N);
    place_all_kernel<<<(hmax + GB - 1) / GB, GB, 0, stream>>>(src, dst, gcn_cnt, gcn_srcs, E,
                                                              hg_row, hg_col, hg_val,
                                                              hgc_cnt, hgr_cnt,
                                                              hgc_ent, hgr_ent, NNZ);

    // --- weight precompute + reassociated GCN ---
    wprep_kernel<<<65, 64, 0, stream>>>(W1, W2, b1, w12, bw);
    gcn_gather_kernel<true><<<(N + 3) / 4, 256, 0, stream>>>(emb, dinv, gcn_off, gcn_srcs,
                                                             tbuf, sdi, N);
    gcn_gather_kernel<false><<<(N + 3) / 4, 256, 0, stream>>>(tbuf, dinv, gcn_off, gcn_srcs,
                                                              ubuf, nullptr, N);
    gemm_h2_kernel<<<(N + 31) / 32, 256, 0, stream>>>(ubuf, w12, bw, b2, sdi, h2, N);

    // --- BatchNorm stats (apply is fused into consumers) ---
    {
        int nblocks = 256;
        int rpb = (N + nblocks - 1) / nblocks;
        bn_stats_kernel<<<nblocks, 256, 0, stream>>>(h2, stats, N, rpb);
    }

    // --- HGNN: edge_emb = G^T relu(bn(h2))+bias ; x2 = G edge_emb ---
    hg_gather_kernel<true><<<(N + 3) / 4, 256, 0, stream>>>(h2, hgc_off, hgc_ent,
                                                            stats, gamma, beta, hgc1_bias,
                                                            invN, eemb, N);
    hg_gather_kernel<false><<<(N + 3) / 4, 256, 0, stream>>>(eemb, hgr_off, hgr_ent,
                                                             nullptr, nullptr, nullptr, nullptr,
                                                             0.f, x2, N);

    // --- fused softmax + fc1 + fusion gate (bn on hidden inline) ---
    tail_kernel<<<(N + 63) / 64, 256, 0, stream>>>(x2, h2, fc1_W, fus_l1_W, fus_l1_b,
                                                   fus_l2_W, fus_l2_b, stats, gamma, beta,
                                                   invN, out, N);
}

// Round 6
// 587.020 us; speedup vs baseline: 5.4800x; 1.1265x over previous
//
#include <hip/hip_runtime.h>
#include <hip/hip_fp16.h>

// ---------------------------------------------------------------------------
// MSHGAT forward, round 6:
//  - XCD-local CSR build: hist/place partitioned into 8 key-range segments,
//    segment = blockIdx & 7 (block->XCD round-robin). Each segment scans the
//    full edge list, places only its key range -> all scattered stores and
//    counter atomics confined to ~1.4MB, one XCD's L2; lines fill fully.
//  - gcn_srcs packed to u16 (N < 65536).
// N=50000, D=64, E=600000, NNZ=800000.
// ---------------------------------------------------------------------------

#define SEGS 8
#define SEGBLK 128   // blocks per segment for hist/place

// ---- segmented histograms (gcn by dst, hg by row and by col) ---------------
__global__ __launch_bounds__(256) void hist_all_kernel(const int* __restrict__ dst, int e,
                                                       const int* __restrict__ row,
                                                       const int* __restrict__ col, int nnz,
                                                       int* __restrict__ cg,
                                                       int* __restrict__ cr,
                                                       int* __restrict__ cc, int keyspan) {
    int seg = blockIdx.x & (SEGS - 1);
    int klo = seg * keyspan, khi = klo + keyspan;
    int base = (blockIdx.x >> 3) * 256 + threadIdx.x;
    const int stride = SEGBLK * 256;
    for (int i = base; i < e; i += stride) {
        int d = dst[i];
        if (d >= klo && d < khi) atomicAdd(&cg[d], 1);
    }
    for (int i = base; i < nnz; i += stride) {
        int r = row[i];
        if (r >= klo && r < khi) atomicAdd(&cr[r], 1);
        int c = col[i];
        if (c >= klo && c < khi) atomicAdd(&cc[c], 1);
    }
}

// ---- 3 independent exclusive scans (block b -> array b) --------------------
// Block 0 additionally writes dinv[i] = rsqrt(indeg + 1) from original counts.
__global__ __launch_bounds__(1024) void scan3_kernel(int* __restrict__ g_cnt, int* __restrict__ g_off,
                                                     int* __restrict__ c_cnt, int* __restrict__ c_off,
                                                     int* __restrict__ r_cnt, int* __restrict__ r_off,
                                                     float* __restrict__ dinv, int n) {
    int which = blockIdx.x;
    int* cnt = (which == 0) ? g_cnt : (which == 1) ? c_cnt : r_cnt;
    int* off = (which == 0) ? g_off : (which == 1) ? c_off : r_off;
    __shared__ int part[1024];
    int tid = threadIdx.x;
    int chunk = (n + 1023) / 1024;
    int s0 = tid * chunk, s1 = s0 + chunk;
    if (s1 > n) s1 = n;
    int sum = 0;
    for (int i = s0; i < s1; ++i) {
        int c = cnt[i];
        sum += c;
        if (which == 0) dinv[i] = rsqrtf((float)(c + 1));
    }
    part[tid] = sum;
    __syncthreads();
    for (int d = 1; d < 1024; d <<= 1) {
        int v = (tid >= d) ? part[tid - d] : 0;
        __syncthreads();
        part[tid] += v;
        __syncthreads();
    }
    int run = (tid == 0) ? 0 : part[tid - 1];
    for (int i = s0; i < s1; ++i) {
        int c = cnt[i];
        off[i] = run;
        cnt[i] = run;   // becomes "cur" for placement
        run += c;
    }
    if (tid == 1023) off[n] = part[1023];
}

// ---- segmented placement (gcn srcs u16 + packed hg entries) -----------------
__global__ __launch_bounds__(256) void place_all_kernel(const int* __restrict__ src,
                                                        const int* __restrict__ dst,
                                                        int* __restrict__ gcur,
                                                        unsigned short* __restrict__ gsrcs, int e,
                                                        const int* __restrict__ row,
                                                        const int* __restrict__ col,
                                                        const float* __restrict__ val,
                                                        int* __restrict__ curc,
                                                        int* __restrict__ curr,
                                                        unsigned* __restrict__ entc,
                                                        unsigned* __restrict__ entr, int nnz,
                                                        int keyspan) {
    int seg = blockIdx.x & (SEGS - 1);
    int klo = seg * keyspan, khi = klo + keyspan;
    int base = (blockIdx.x >> 3) * 256 + threadIdx.x;
    const int stride = SEGBLK * 256;
    for (int i = base; i < e; i += stride) {
        int d = dst[i];
        if (d >= klo && d < khi) {
            int pos = atomicAdd(&gcur[d], 1);
            gsrcs[pos] = (unsigned short)src[i];
        }
    }
    for (int i = base; i < nnz; i += stride) {
        int r = row[i], c = col[i];
        bool inc = (c >= klo && c < khi);
        bool inr = (r >= klo && r < khi);
        if (inc || inr) {
            unsigned hv = (unsigned)__half_as_ushort(__float2half(val[i]));
            if (inc) {
                int pc = atomicAdd(&curc[c], 1);
                entc[pc] = ((unsigned)r << 16) | hv;    // CSR by col: (row, val)
            }
            if (inr) {
                int pr = atomicAdd(&curr[r], 1);
                entr[pr] = ((unsigned)c << 16) | hv;    // CSR by row: (col, val)
            }
        }
    }
}

// ---- weight precompute: W12 = W1@W2 (64x64), bw = b1@W2 (64) ----------------
__global__ __launch_bounds__(64) void wprep_kernel(const float* __restrict__ W1,  // 64x128
                                                   const float* __restrict__ W2,  // 128x64
                                                   const float* __restrict__ b1,  // 128
                                                   float* __restrict__ W12,
                                                   float* __restrict__ bw) {
    int r = blockIdx.x;
    int c = threadIdx.x;
    const float* a = (r < 64) ? (W1 + r * 128) : b1;
    float acc = 0.f;
#pragma unroll 8
    for (int k = 0; k < 128; ++k) acc = fmaf(a[k], W2[k * 64 + c], acc);
    if (r < 64) W12[r * 64 + c] = acc;
    else bw[c] = acc;
}

// ---- GCN gather (normalized):
// out_i = dinv_i * (dinv_i * x_i + sum_e dinv_s * x_s)
// SDI: also sdi_i = dinv_i * (dinv_i + sum_e dinv_s)  == rowsum(A-hat)_i
template <bool SDI>
__global__ __launch_bounds__(256) void gcn_gather_kernel(const float* __restrict__ x,
                                                         const float* __restrict__ dinv,
                                                         const int* __restrict__ off,
                                                         const unsigned short* __restrict__ srcs,
                                                         float* __restrict__ out,
                                                         float* __restrict__ sdi, int n) {
    int node = blockIdx.x * 4 + (threadIdx.x >> 6);
    if (node >= n) return;
    int lane = threadIdx.x & 63;
    int sub = lane >> 4;
    int q = lane & 15;
    int e0 = off[node], e1 = off[node + 1];
    float4 acc = make_float4(0.f, 0.f, 0.f, 0.f);
    float dsum = 0.f;
    int e = e0 + sub;
    int s = (e < e1) ? (int)srcs[e] : 0;
    float ds = (e < e1) ? dinv[s] : 0.f;
    for (; e < e1; e += 4) {
        int sn = (e + 4 < e1) ? (int)srcs[e + 4] : 0;
        float dsn = (e + 4 < e1) ? dinv[sn] : 0.f;
        const float4 v = *(const float4*)(x + (long long)s * 64 + q * 4);
        acc.x = fmaf(ds, v.x, acc.x);
        acc.y = fmaf(ds, v.y, acc.y);
        acc.z = fmaf(ds, v.z, acc.z);
        acc.w = fmaf(ds, v.w, acc.w);
        dsum += ds;
        s = sn; ds = dsn;
    }
    acc.x += __shfl_xor(acc.x, 16, 64); acc.x += __shfl_xor(acc.x, 32, 64);
    acc.y += __shfl_xor(acc.y, 16, 64); acc.y += __shfl_xor(acc.y, 32, 64);
    acc.z += __shfl_xor(acc.z, 16, 64); acc.z += __shfl_xor(acc.z, 32, 64);
    acc.w += __shfl_xor(acc.w, 16, 64); acc.w += __shfl_xor(acc.w, 32, 64);
    if (SDI) { dsum += __shfl_xor(dsum, 16, 64); dsum += __shfl_xor(dsum, 32, 64); }
    if (sub == 0) {
        float dt = dinv[node];
        const float4 xs = *(const float4*)(x + (long long)node * 64 + q * 4);
        float4 o;
        o.x = dt * fmaf(dt, xs.x, acc.x);
        o.y = dt * fmaf(dt, xs.y, acc.y);
        o.z = dt * fmaf(dt, xs.z, acc.z);
        o.w = dt * fmaf(dt, xs.w, acc.w);
        *(float4*)(out + (long long)node * 64 + q * 4) = o;
        if (SDI && q == 0) sdi[node] = dt * (dt + dsum);
    }
}

// ---- GEMM h2 = u @ W12 + sdi[r]*bw + b2 -------------------------------------
__global__ __launch_bounds__(256) void gemm_h2_kernel(const float* __restrict__ X,
                                                      const float* __restrict__ W12,
                                                      const float* __restrict__ bw,
                                                      const float* __restrict__ b2,
                                                      const float* __restrict__ sdi,
                                                      float* __restrict__ h2, int n) {
    __shared__ float Wl[64 * 64];
    __shared__ float cadd[64], b2l[64];
    for (int i = threadIdx.x; i < 4096; i += 256) Wl[i] = W12[i];
    if (threadIdx.x < 64) cadd[threadIdx.x] = bw[threadIdx.x];
    else if (threadIdx.x < 128) b2l[threadIdx.x - 64] = b2[threadIdx.x - 64];
    __syncthreads();
    int m = threadIdx.x & 63;
    int rend = (blockIdx.x + 1) * 32; if (rend > n) rend = n;
    for (int r = blockIdx.x * 32 + (threadIdx.x >> 6); r < rend; r += 4) {
        const float* xr = X + (long long)r * 64;
        float acc = 0.0f;
#pragma unroll 8
        for (int k = 0; k < 64; ++k) acc = fmaf(xr[k], Wl[k * 64 + m], acc);
        h2[(long long)r * 64 + m] = acc + sdi[r] * cadd[m] + b2l[m];
    }
}

// ---- BatchNorm stats (over raw h2) ------------------------------------------
__global__ __launch_bounds__(256) void bn_stats_kernel(const float* __restrict__ h2,
                                                       float* __restrict__ stats,
                                                       int nrows, int rpb) {
    int col = threadIdx.x & 63;
    int grp = threadIdx.x >> 6;
    int r0 = blockIdx.x * rpb;
    int r1 = r0 + rpb; if (r1 > nrows) r1 = nrows;
    float s = 0.0f, s2 = 0.0f;
    for (int r = r0 + grp; r < r1; r += 4) {
        float v = h2[(long long)r * 64 + col];
        s += v; s2 += v * v;
    }
    __shared__ float ls[4][64], ls2[4][64];
    ls[grp][col] = s; ls2[grp][col] = s2;
    __syncthreads();
    if (grp == 0) {
        s  = ls[0][col] + ls[1][col] + ls[2][col] + ls[3][col];
        s2 = ls2[0][col] + ls2[1][col] + ls2[2][col] + ls2[3][col];
        atomicAdd(&stats[col], s);
        atomicAdd(&stats[64 + col], s2);
    }
}

// ---- HGNN gather; BN=true applies bn+relu+hgc1_bias to gathered rows --------
template <bool BN>
__global__ __launch_bounds__(256) void hg_gather_kernel(const float* __restrict__ in,
                                                        const int* __restrict__ off,
                                                        const unsigned* __restrict__ ents,
                                                        const float* __restrict__ stats,
                                                        const float* __restrict__ gamma,
                                                        const float* __restrict__ beta,
                                                        const float* __restrict__ hbias,
                                                        float invN,
                                                        float* __restrict__ out, int n) {
    int node = blockIdx.x * 4 + (threadIdx.x >> 6);
    if (node >= n) return;
    int lane = threadIdx.x & 63;
    int sub = lane >> 4;
    int q = lane & 15;
    float sc[4], sh[4], hb[4];
    if (BN) {
#pragma unroll
        for (int c = 0; c < 4; ++c) {
            int col = q * 4 + c;
            float mu = stats[col] * invN;
            float var = stats[64 + col] * invN - mu * mu;
            float s = gamma[col] * rsqrtf(var + 1e-5f);
            sc[c] = s; sh[c] = beta[col] - mu * s; hb[c] = hbias[col];
        }
    }
    int e0 = off[node], e1 = off[node + 1];
    float4 acc = make_float4(0.f, 0.f, 0.f, 0.f);
    int e = e0 + sub;
    unsigned t = (e < e1) ? ents[e] : 0u;
    for (; e < e1; e += 4) {
        unsigned tn = (e + 4 < e1) ? ents[e + 4] : 0u;
        float vv = __half2float(__ushort_as_half((unsigned short)(t & 0xffffu)));
        float4 v = *(const float4*)(in + (long long)(t >> 16) * 64 + q * 4);
        if (BN) {
            v.x = fmaxf(fmaf(v.x, sc[0], sh[0]), 0.f) + hb[0];
            v.y = fmaxf(fmaf(v.y, sc[1], sh[1]), 0.f) + hb[1];
            v.z = fmaxf(fmaf(v.z, sc[2], sh[2]), 0.f) + hb[2];
            v.w = fmaxf(fmaf(v.w, sc[3], sh[3]), 0.f) + hb[3];
        }
        acc.x = fmaf(vv, v.x, acc.x);
        acc.y = fmaf(vv, v.y, acc.y);
        acc.z = fmaf(vv, v.z, acc.z);
        acc.w = fmaf(vv, v.w, acc.w);
        t = tn;
    }
    acc.x += __shfl_xor(acc.x, 16, 64); acc.x += __shfl_xor(acc.x, 32, 64);
    acc.y += __shfl_xor(acc.y, 16, 64); acc.y += __shfl_xor(acc.y, 32, 64);
    acc.z += __shfl_xor(acc.z, 16, 64); acc.z += __shfl_xor(acc.z, 32, 64);
    acc.w += __shfl_xor(acc.w, 16, 64); acc.w += __shfl_xor(acc.w, 32, 64);
    if (sub == 0) *(float4*)(out + (long long)node * 64 + q * 4) = acc;
}

// ---- fused tail: softmax -> fc1 -> fusion gate; bn applied to hidden --------
#define TPAD 68
__device__ __forceinline__ float dot4(float4 a, float4 b) {
    return fmaf(a.x, b.x, fmaf(a.y, b.y, fmaf(a.z, b.z, a.w * b.w)));
}

__global__ __launch_bounds__(256) void tail_kernel(const float* __restrict__ x2,
                                                   const float* __restrict__ h2raw,
                                                   const float* __restrict__ fc1_W,
                                                   const float* __restrict__ fusW1,
                                                   const float* __restrict__ b1,
                                                   const float* __restrict__ w2,
                                                   const float* __restrict__ b2,
                                                   const float* __restrict__ stats,
                                                   const float* __restrict__ gamma,
                                                   const float* __restrict__ beta,
                                                   float invN,
                                                   float* __restrict__ out, int n) {
    __shared__ float A[64 * TPAD];    // P (softmax probs), later S (subn)
    __shared__ float Hs[64 * TPAD];   // hidden tile (bn applied)
    __shared__ float WL[64 * TPAD];   // fc1_W, later fus_l1_W
    __shared__ float bsc[64], bsh[64];
    int t = threadIdx.x;
    int tx = t & 15, ty = t >> 4;
    int r0 = blockIdx.x * 64;

    if (t < 64) {
        float mu = stats[t] * invN;
        float var = stats[64 + t] * invN - mu * mu;
        float s = gamma[t] * rsqrtf(var + 1e-5f);
        bsc[t] = s; bsh[t] = beta[t] - mu * s;
    }
    __syncthreads();

    float b1d[4], w2d[4];
#pragma unroll
    for (int di = 0; di < 4; ++di) {
        b1d[di] = b1[tx + 16 * di];
        w2d[di] = w2[tx + 16 * di];
    }
    float b20 = b2[0];

    // fc1 weights -> WL ; bn(hidden) tile -> Hs
    for (int f = t; f < 1024; f += 256) {
        int d = f >> 4, k4 = (f & 15) << 2;
        *(float4*)&WL[d * TPAD + k4] = *(const float4*)&fc1_W[d * 64 + k4];
        int gr = r0 + d;
        float4 hv = make_float4(0.f, 0.f, 0.f, 0.f);
        if (gr < n) {
            hv = *(const float4*)&h2raw[(long long)gr * 64 + k4];
            hv.x = fmaf(hv.x, bsc[k4],     bsh[k4]);
            hv.y = fmaf(hv.y, bsc[k4 + 1], bsh[k4 + 1]);
            hv.z = fmaf(hv.z, bsc[k4 + 2], bsh[k4 + 2]);
            hv.w = fmaf(hv.w, bsc[k4 + 3], bsh[k4 + 3]);
        }
        *(float4*)&Hs[d * TPAD + k4] = hv;
    }

    // x2 tile: load + row softmax -> A
#pragma unroll
    for (int ri = 0; ri < 4; ++ri) {
        int rl = 4 * ty + ri;
        int r = r0 + rl;
        bool ok = r < n;
        float vv[4];
#pragma unroll
        for (int di = 0; di < 4; ++di)
            vv[di] = ok ? x2[(long long)r * 64 + tx + 16 * di] : 0.f;
        float m = fmaxf(fmaxf(vv[0], vv[1]), fmaxf(vv[2], vv[3]));
        for (int s = 1; s < 16; s <<= 1) m = fmaxf(m, __shfl_xor(m, s, 16));
        float e0 = expf(vv[0] - m), e1 = expf(vv[1] - m);
        float e2 = expf(vv[2] - m), e3 = expf(vv[3] - m);
        float sm = e0 + e1 + e2 + e3;
        for (int s = 1; s < 16; s <<= 1) sm += __shfl_xor(sm, s, 16);
        float inv = 1.0f / sm;
        A[rl * TPAD + tx]      = e0 * inv;
        A[rl * TPAD + tx + 16] = e1 * inv;
        A[rl * TPAD + tx + 32] = e2 * inv;
        A[rl * TPAD + tx + 48] = e3 * inv;
    }
    __syncthreads();

    // fc1: sn = P @ fc1_W^T
    float sn[4][4];
#pragma unroll
    for (int ri = 0; ri < 4; ++ri)
#pragma unroll
        for (int di = 0; di < 4; ++di) sn[ri][di] = 0.f;
    for (int k = 0; k < 64; k += 4) {
        float4 p4[4], w4[4];
#pragma unroll
        for (int ri = 0; ri < 4; ++ri) p4[ri] = *(float4*)&A[(4 * ty + ri) * TPAD + k];
#pragma unroll
        for (int di = 0; di < 4; ++di) w4[di] = *(float4*)&WL[(tx + 16 * di) * TPAD + k];
#pragma unroll
        for (int ri = 0; ri < 4; ++ri)
#pragma unroll
            for (int di = 0; di < 4; ++di)
                sn[ri][di] += dot4(p4[ri], w4[di]);
    }
    __syncthreads();

    // S (subn) -> A ; fus_l1_W -> WL
#pragma unroll
    for (int ri = 0; ri < 4; ++ri)
#pragma unroll
        for (int di = 0; di < 4; ++di)
            A[(4 * ty + ri) * TPAD + tx + 16 * di] = sn[ri][di];
    for (int f = t; f < 1024; f += 256) {
        int d = f >> 4, k4 = (f & 15) << 2;
        *(float4*)&WL[d * TPAD + k4] = *(const float4*)&fusW1[d * 64 + k4];
    }
    __syncthreads();

    // gates
    float aH[4][4], aS[4][4];
#pragma unroll
    for (int ri = 0; ri < 4; ++ri)
#pragma unroll
        for (int di = 0; di < 4; ++di) { aH[ri][di] = b1d[di]; aS[ri][di] = b1d[di]; }
    for (int k = 0; k < 64; k += 4) {
        float4 h4[4], s4[4], w4[4];
#pragma unroll
        for (int ri = 0; ri < 4; ++ri) {
            h4[ri] = *(float4*)&Hs[(4 * ty + ri) * TPAD + k];
            s4[ri] = *(float4*)&A[(4 * ty + ri) * TPAD + k];
        }
#pragma unroll
        for (int di = 0; di < 4; ++di) w4[di] = *(float4*)&WL[(tx + 16 * di) * TPAD + k];
#pragma unroll
        for (int ri = 0; ri < 4; ++ri)
#pragma unroll
            for (int di = 0; di < 4; ++di) {
                aH[ri][di] += dot4(h4[ri], w4[di]);
                aS[ri][di] += dot4(s4[ri], w4[di]);
            }
    }

#pragma unroll
    for (int ri = 0; ri < 4; ++ri) {
        int rl = 4 * ty + ri;
        int r = r0 + rl;
        float pH = 0.f, pS = 0.f;
#pragma unroll
        for (int di = 0; di < 4; ++di) {
            pH = fmaf(tanhf(aH[ri][di]), w2d[di], pH);
            pS = fmaf(tanhf(aS[ri][di]), w2d[di], pS);
        }
        for (int s = 1; s < 16; s <<= 1) {
            pH += __shfl_xor(pH, s, 16);
            pS += __shfl_xor(pS, s, 16);
        }
        pH += b20; pS += b20;
        float mx = fmaxf(pH, pS);
        float eH = expf(pH - mx), eS = expf(pS - mx);
        float inv = 1.0f / (eH + eS);
        if (r < n) {
#pragma unroll
            for (int di = 0; di < 4; ++di) {
                int d = tx + 16 * di;
                float hv = Hs[rl * TPAD + d];
                out[(long long)r * 64 + d] = (eH * hv + eS * sn[ri][di]) * inv;
            }
        }
    }
}

// ---------------------------------------------------------------------------
extern "C" void kernel_launch(void* const* d_in, const int* in_sizes, int n_in,
                              void* d_out, int out_size, void* d_ws, size_t ws_size,
                              hipStream_t stream) {
    const float* emb       = (const float*)d_in[0];
    const float* W1        = (const float*)d_in[1];
    const float* b1        = (const float*)d_in[2];
    const float* W2        = (const float*)d_in[3];
    const float* b2        = (const float*)d_in[4];
    const float* gamma     = (const float*)d_in[5];
    const float* beta      = (const float*)d_in[6];
    const float* hgc1_bias = (const float*)d_in[7];
    const float* fc1_W     = (const float*)d_in[8];
    const float* fus_l1_W  = (const float*)d_in[9];
    const float* fus_l1_b  = (const float*)d_in[10];
    const float* fus_l2_W  = (const float*)d_in[11];
    const float* fus_l2_b  = (const float*)d_in[12];
    const float* hg_val    = (const float*)d_in[13];
    const int*   edge_index= (const int*)d_in[14];
    const int*   hg_row    = (const int*)d_in[15];
    const int*   hg_col    = (const int*)d_in[16];

    const int N   = in_sizes[0] / 64;
    const int E   = in_sizes[14] / 2;
    const int NNZ = in_sizes[13];
    const int Np  = (N + 3) & ~3;            // 16B-aligned strides
    const int keyspan = (N + SEGS - 1) / SEGS;
    const int* src = edge_index;
    const int* dst = edge_index + E;

    // workspace layout (4B units, all offsets multiples of 4):
    // dinv Np | sdi Np | w12 4096 | bw 64 |
    // Z: [stats 128 | gcn_cnt Np | hgc_cnt Np | hgr_cnt Np]   <- single memset
    // gcn_off Np+4 | hgc_off Np+4 | hgr_off Np+4 |
    // gcn_srcs E/2 (u16) | hgc_ent NNZ | hgr_ent NNZ | buf1 128*Np | buf2 64*Np
    float* ws      = (float*)d_ws;
    float* dinv    = ws;
    float* sdi     = dinv + Np;
    float* w12     = sdi + Np;
    float* bw      = w12 + 4096;
    float* stats   = bw + 64;
    int*   gcn_cnt = (int*)(stats + 128);
    int*   hgc_cnt = gcn_cnt + Np;
    int*   hgr_cnt = hgc_cnt + Np;
    int*   gcn_off = hgr_cnt + Np;
    int*   hgc_off = gcn_off + (Np + 4);
    int*   hgr_off = hgc_off + (Np + 4);
    unsigned short* gcn_srcs = (unsigned short*)(hgr_off + (Np + 4));
    unsigned* hgc_ent = (unsigned*)(gcn_srcs + ((E + 1) & ~1));
    unsigned* hgr_ent = hgc_ent + NNZ;
    float* buf1    = (float*)(hgr_ent + NNZ);
    float* buf2    = buf1 + (size_t)128 * Np;

    float* tbuf = buf2;                      // A-hat emb        N x 64
    float* ubuf = buf1;                      // A-hat^2 emb      N x 64
    float* h2   = buf1 + (size_t)64 * Np;    // raw h2 (pre-bn)  N x 64
    float* eemb = buf2;                      // edge emb         N x 64 (tbuf dead)
    float* x2   = buf1;                      // HGNN out         N x 64 (ubuf dead)
    float* out  = (float*)d_out;

    const float invN = 1.0f / (float)N;

    // --- CSR builds (XCD-local segmented) ---
    hipMemsetAsync(stats, 0, (size_t)(128 + 3 * Np) * sizeof(int), stream);
    hist_all_kernel<<<SEGS * SEGBLK, 256, 0, stream>>>(dst, E, hg_row, hg_col, NNZ,
                                                       gcn_cnt, hgr_cnt, hgc_cnt, keyspan);
    scan3_kernel<<<3, 1024, 0, stream>>>(gcn_cnt, gcn_off, hgc_cnt, hgc_off,
                                         hgr_cnt, hgr_off, dinv, N);
    place_all_kernel<<<SEGS * SEGBLK, 256, 0, stream>>>(src, dst, gcn_cnt, gcn_srcs, E,
                                                        hg_row, hg_col, hg_val,
                                                        hgc_cnt, hgr_cnt,
                                                        hgc_ent, hgr_ent, NNZ, keyspan);

    // --- weight precompute + reassociated GCN ---
    wprep_kernel<<<65, 64, 0, stream>>>(W1, W2, b1, w12, bw);
    gcn_gather_kernel<true><<<(N + 3) / 4, 256, 0, stream>>>(emb, dinv, gcn_off, gcn_srcs,
                                                             tbuf, sdi, N);
    gcn_gather_kernel<false><<<(N + 3) / 4, 256, 0, stream>>>(tbuf, dinv, gcn_off, gcn_srcs,
                                                              ubuf, nullptr, N);
    gemm_h2_kernel<<<(N + 31) / 32, 256, 0, stream>>>(ubuf, w12, bw, b2, sdi, h2, N);

    // --- BatchNorm stats (apply is fused into consumers) ---
    {
        int nblocks = 256;
        int rpb = (N + nblocks - 1) / nblocks;
        bn_stats_kernel<<<nblocks, 256, 0, stream>>>(h2, stats, N, rpb);
    }

    // --- HGNN: edge_emb = G^T relu(bn(h2))+bias ; x2 = G edge_emb ---
    hg_gather_kernel<true><<<(N + 3) / 4, 256, 0, stream>>>(h2, hgc_off, hgc_ent,
                                                            stats, gamma, beta, hgc1_bias,
                                                            invN, eemb, N);
    hg_gather_kernel<false><<<(N + 3) / 4, 256, 0, stream>>>(eemb, hgr_off, hgr_ent,
                                                             nullptr, nullptr, nullptr, nullptr,
                                                             0.f, x2, N);

    // --- fused softmax + fc1 + fusion gate (bn on hidden inline) ---
    tail_kernel<<<(N + 63) / 64, 256, 0, stream>>>(x2, h2, fc1_W, fus_l1_W, fus_l1_b,
                                                   fus_l2_W, fus_l2_b, stats, gamma, beta,
                                                   invN, out, N);
}

// Round 7
// 435.178 us; speedup vs baseline: 7.3921x; 1.3489x over previous
//
#include <hip/hip_runtime.h>
#include <hip/hip_fp16.h>

// ---------------------------------------------------------------------------
// MSHGAT forward, round 7:
//  - scan3 (3 blocks, latency-starved, 164us) replaced by two-phase decoupled
//    scan: scan_part (block partials, int4 chunks) + scan_apply (wave-reduced
//    base + 256-wide Hillis-Steele), 3*49 blocks each.
//  - rest unchanged from round 6 (XCD-segmented CSR build, reassociated GCN,
//    fused BN, fused tail).
// N=50000, D=64, E=600000, NNZ=800000.
// ---------------------------------------------------------------------------

#define SEGS 8
#define SEGBLK 128   // blocks per segment for hist/place
#define SCHUNK 1024  // elements per scan block (4 per thread); PB = ceil(N/1024) <= 64 required

// ---- segmented histograms (gcn by dst, hg by row and by col) ---------------
__global__ __launch_bounds__(256) void hist_all_kernel(const int* __restrict__ dst, int e,
                                                       const int* __restrict__ row,
                                                       const int* __restrict__ col, int nnz,
                                                       int* __restrict__ cg,
                                                       int* __restrict__ cr,
                                                       int* __restrict__ cc, int keyspan) {
    int seg = blockIdx.x & (SEGS - 1);
    int klo = seg * keyspan, khi = klo + keyspan;
    int base = (blockIdx.x >> 3) * 256 + threadIdx.x;
    const int stride = SEGBLK * 256;
    for (int i = base; i < e; i += stride) {
        int d = dst[i];
        if (d >= klo && d < khi) atomicAdd(&cg[d], 1);
    }
    for (int i = base; i < nnz; i += stride) {
        int r = row[i];
        if (r >= klo && r < khi) atomicAdd(&cr[r], 1);
        int c = col[i];
        if (c >= klo && c < khi) atomicAdd(&cc[c], 1);
    }
}

// ---- two-phase decoupled scan (3 arrays) ------------------------------------
// phase 1: per-block partial sums
__global__ __launch_bounds__(256) void scan_part_kernel(const int* __restrict__ g_cnt,
                                                        const int* __restrict__ c_cnt,
                                                        const int* __restrict__ r_cnt,
                                                        int* __restrict__ partials,
                                                        int n, int pb) {
    int which = blockIdx.x / pb, blk = blockIdx.x % pb;
    const int* cnt = (which == 0) ? g_cnt : (which == 1) ? c_cnt : r_cnt;
    int i0 = blk * SCHUNK + threadIdx.x * 4;
    int4 v = make_int4(0, 0, 0, 0);
    if (i0 + 3 < n) v = *(const int4*)(cnt + i0);
    else {
        if (i0 < n)     v.x = cnt[i0];
        if (i0 + 1 < n) v.y = cnt[i0 + 1];
        if (i0 + 2 < n) v.z = cnt[i0 + 2];
    }
    int s = v.x + v.y + v.z + v.w;
    __shared__ int red[256];
    red[threadIdx.x] = s;
    __syncthreads();
    for (int d = 128; d; d >>= 1) {
        if (threadIdx.x < d) red[threadIdx.x] += red[threadIdx.x + d];
        __syncthreads();
    }
    if (threadIdx.x == 0) partials[blockIdx.x] = red[0];
}

// phase 2: base from preceding partials (wave reduce) + block-local scan
__global__ __launch_bounds__(256) void scan_apply_kernel(int* __restrict__ g_cnt, int* __restrict__ g_off,
                                                         int* __restrict__ c_cnt, int* __restrict__ c_off,
                                                         int* __restrict__ r_cnt, int* __restrict__ r_off,
                                                         const int* __restrict__ partials,
                                                         float* __restrict__ dinv, int n, int pb) {
    int which = blockIdx.x / pb, blk = blockIdx.x % pb;
    int* cnt = (which == 0) ? g_cnt : (which == 1) ? c_cnt : r_cnt;
    int* off = (which == 0) ? g_off : (which == 1) ? c_off : r_off;
    __shared__ int sbase, stotal;
    __shared__ int sc[256];
    int tid = threadIdx.x;
    if (tid < 64) {
        int lane = tid;
        int p = (lane < pb) ? partials[which * pb + lane] : 0;
        int pre = (lane < blk) ? p : 0;
        int tot = p;
        for (int d = 32; d; d >>= 1) {
            pre += __shfl_xor(pre, d, 64);
            tot += __shfl_xor(tot, d, 64);
        }
        if (tid == 0) { sbase = pre; stotal = tot; }
    }
    int i0 = blk * SCHUNK + tid * 4;
    int4 v = make_int4(0, 0, 0, 0);
    if (i0 + 3 < n) v = *(const int4*)(cnt + i0);
    else {
        if (i0 < n)     v.x = cnt[i0];
        if (i0 + 1 < n) v.y = cnt[i0 + 1];
        if (i0 + 2 < n) v.z = cnt[i0 + 2];
    }
    int s = v.x + v.y + v.z + v.w;
    sc[tid] = s;
    __syncthreads();
    for (int d = 1; d < 256; d <<= 1) {
        int t = (tid >= d) ? sc[tid - d] : 0;
        __syncthreads();
        sc[tid] += t;
        __syncthreads();
    }
    int run = sbase + sc[tid] - s;   // exclusive prefix
    int cv[4] = {v.x, v.y, v.z, v.w};
#pragma unroll
    for (int k = 0; k < 4; ++k) {
        int i = i0 + k;
        if (i < n) {
            off[i] = run;
            if (which == 0) dinv[i] = rsqrtf((float)(cv[k] + 1));
            cnt[i] = run;   // becomes "cur" for placement
            run += cv[k];
        }
    }
    if (blk == 0 && tid == 0) off[n] = stotal;
}

// ---- segmented placement (gcn srcs u16 + packed hg entries) -----------------
__global__ __launch_bounds__(256) void place_all_kernel(const int* __restrict__ src,
                                                        const int* __restrict__ dst,
                                                        int* __restrict__ gcur,
                                                        unsigned short* __restrict__ gsrcs, int e,
                                                        const int* __restrict__ row,
                                                        const int* __restrict__ col,
                                                        const float* __restrict__ val,
                                                        int* __restrict__ curc,
                                                        int* __restrict__ curr,
                                                        unsigned* __restrict__ entc,
                                                        unsigned* __restrict__ entr, int nnz,
                                                        int keyspan) {
    int seg = blockIdx.x & (SEGS - 1);
    int klo = seg * keyspan, khi = klo + keyspan;
    int base = (blockIdx.x >> 3) * 256 + threadIdx.x;
    const int stride = SEGBLK * 256;
    for (int i = base; i < e; i += stride) {
        int d = dst[i];
        if (d >= klo && d < khi) {
            int pos = atomicAdd(&gcur[d], 1);
            gsrcs[pos] = (unsigned short)src[i];
        }
    }
    for (int i = base; i < nnz; i += stride) {
        int r = row[i], c = col[i];
        bool inc = (c >= klo && c < khi);
        bool inr = (r >= klo && r < khi);
        if (inc || inr) {
            unsigned hv = (unsigned)__half_as_ushort(__float2half(val[i]));
            if (inc) {
                int pc = atomicAdd(&curc[c], 1);
                entc[pc] = ((unsigned)r << 16) | hv;    // CSR by col: (row, val)
            }
            if (inr) {
                int pr = atomicAdd(&curr[r], 1);
                entr[pr] = ((unsigned)c << 16) | hv;    // CSR by row: (col, val)
            }
        }
    }
}

// ---- weight precompute: W12 = W1@W2 (64x64), bw = b1@W2 (64) ----------------
__global__ __launch_bounds__(64) void wprep_kernel(const float* __restrict__ W1,  // 64x128
                                                   const float* __restrict__ W2,  // 128x64
                                                   const float* __restrict__ b1,  // 128
                                                   float* __restrict__ W12,
                                                   float* __restrict__ bw) {
    int r = blockIdx.x;
    int c = threadIdx.x;
    const float* a = (r < 64) ? (W1 + r * 128) : b1;
    float acc = 0.f;
#pragma unroll 8
    for (int k = 0; k < 128; ++k) acc = fmaf(a[k], W2[k * 64 + c], acc);
    if (r < 64) W12[r * 64 + c] = acc;
    else bw[c] = acc;
}

// ---- GCN gather (normalized):
// out_i = dinv_i * (dinv_i * x_i + sum_e dinv_s * x_s)
// SDI: also sdi_i = dinv_i * (dinv_i + sum_e dinv_s)  == rowsum(A-hat)_i
template <bool SDI>
__global__ __launch_bounds__(256) void gcn_gather_kernel(const float* __restrict__ x,
                                                         const float* __restrict__ dinv,
                                                         const int* __restrict__ off,
                                                         const unsigned short* __restrict__ srcs,
                                                         float* __restrict__ out,
                                                         float* __restrict__ sdi, int n) {
    int node = blockIdx.x * 4 + (threadIdx.x >> 6);
    if (node >= n) return;
    int lane = threadIdx.x & 63;
    int sub = lane >> 4;
    int q = lane & 15;
    int e0 = off[node], e1 = off[node + 1];
    float4 acc = make_float4(0.f, 0.f, 0.f, 0.f);
    float dsum = 0.f;
    int e = e0 + sub;
    int s = (e < e1) ? (int)srcs[e] : 0;
    float ds = (e < e1) ? dinv[s] : 0.f;
    for (; e < e1; e += 4) {
        int sn = (e + 4 < e1) ? (int)srcs[e + 4] : 0;
        float dsn = (e + 4 < e1) ? dinv[sn] : 0.f;
        const float4 v = *(const float4*)(x + (long long)s * 64 + q * 4);
        acc.x = fmaf(ds, v.x, acc.x);
        acc.y = fmaf(ds, v.y, acc.y);
        acc.z = fmaf(ds, v.z, acc.z);
        acc.w = fmaf(ds, v.w, acc.w);
        dsum += ds;
        s = sn; ds = dsn;
    }
    acc.x += __shfl_xor(acc.x, 16, 64); acc.x += __shfl_xor(acc.x, 32, 64);
    acc.y += __shfl_xor(acc.y, 16, 64); acc.y += __shfl_xor(acc.y, 32, 64);
    acc.z += __shfl_xor(acc.z, 16, 64); acc.z += __shfl_xor(acc.z, 32, 64);
    acc.w += __shfl_xor(acc.w, 16, 64); acc.w += __shfl_xor(acc.w, 32, 64);
    if (SDI) { dsum += __shfl_xor(dsum, 16, 64); dsum += __shfl_xor(dsum, 32, 64); }
    if (sub == 0) {
        float dt = dinv[node];
        const float4 xs = *(const float4*)(x + (long long)node * 64 + q * 4);
        float4 o;
        o.x = dt * fmaf(dt, xs.x, acc.x);
        o.y = dt * fmaf(dt, xs.y, acc.y);
        o.z = dt * fmaf(dt, xs.z, acc.z);
        o.w = dt * fmaf(dt, xs.w, acc.w);
        *(float4*)(out + (long long)node * 64 + q * 4) = o;
        if (SDI && q == 0) sdi[node] = dt * (dt + dsum);
    }
}

// ---- GEMM h2 = u @ W12 + sdi[r]*bw + b2 -------------------------------------
__global__ __launch_bounds__(256) void gemm_h2_kernel(const float* __restrict__ X,
                                                      const float* __restrict__ W12,
                                                      const float* __restrict__ bw,
                                                      const float* __restrict__ b2,
                                                      const float* __restrict__ sdi,
                                                      float* __restrict__ h2, int n) {
    __shared__ float Wl[64 * 64];
    __shared__ float cadd[64], b2l[64];
    for (int i = threadIdx.x; i < 4096; i += 256) Wl[i] = W12[i];
    if (threadIdx.x < 64) cadd[threadIdx.x] = bw[threadIdx.x];
    else if (threadIdx.x < 128) b2l[threadIdx.x - 64] = b2[threadIdx.x - 64];
    __syncthreads();
    int m = threadIdx.x & 63;
    int rend = (blockIdx.x + 1) * 32; if (rend > n) rend = n;
    for (int r = blockIdx.x * 32 + (threadIdx.x >> 6); r < rend; r += 4) {
        const float* xr = X + (long long)r * 64;
        float acc = 0.0f;
#pragma unroll 8
        for (int k = 0; k < 64; ++k) acc = fmaf(xr[k], Wl[k * 64 + m], acc);
        h2[(long long)r * 64 + m] = acc + sdi[r] * cadd[m] + b2l[m];
    }
}

// ---- BatchNorm stats (over raw h2) ------------------------------------------
__global__ __launch_bounds__(256) void bn_stats_kernel(const float* __restrict__ h2,
                                                       float* __restrict__ stats,
                                                       int nrows, int rpb) {
    int col = threadIdx.x & 63;
    int grp = threadIdx.x >> 6;
    int r0 = blockIdx.x * rpb;
    int r1 = r0 + rpb; if (r1 > nrows) r1 = nrows;
    float s = 0.0f, s2 = 0.0f;
    for (int r = r0 + grp; r < r1; r += 4) {
        float v = h2[(long long)r * 64 + col];
        s += v; s2 += v * v;
    }
    __shared__ float ls[4][64], ls2[4][64];
    ls[grp][col] = s; ls2[grp][col] = s2;
    __syncthreads();
    if (grp == 0) {
        s  = ls[0][col] + ls[1][col] + ls[2][col] + ls[3][col];
        s2 = ls2[0][col] + ls2[1][col] + ls2[2][col] + ls2[3][col];
        atomicAdd(&stats[col], s);
        atomicAdd(&stats[64 + col], s2);
    }
}

// ---- HGNN gather; BN=true applies bn+relu+hgc1_bias to gathered rows --------
template <bool BN>
__global__ __launch_bounds__(256) void hg_gather_kernel(const float* __restrict__ in,
                                                        const int* __restrict__ off,
                                                        const unsigned* __restrict__ ents,
                                                        const float* __restrict__ stats,
                                                        const float* __restrict__ gamma,
                                                        const float* __restrict__ beta,
                                                        const float* __restrict__ hbias,
                                                        float invN,
                                                        float* __restrict__ out, int n) {
    int node = blockIdx.x * 4 + (threadIdx.x >> 6);
    if (node >= n) return;
    int lane = threadIdx.x & 63;
    int sub = lane >> 4;
    int q = lane & 15;
    float sc[4], sh[4], hb[4];
    if (BN) {
#pragma unroll
        for (int c = 0; c < 4; ++c) {
            int col = q * 4 + c;
            float mu = stats[col] * invN;
            float var = stats[64 + col] * invN - mu * mu;
            float s = gamma[col] * rsqrtf(var + 1e-5f);
            sc[c] = s; sh[c] = beta[col] - mu * s; hb[c] = hbias[col];
        }
    }
    int e0 = off[node], e1 = off[node + 1];
    float4 acc = make_float4(0.f, 0.f, 0.f, 0.f);
    int e = e0 + sub;
    unsigned t = (e < e1) ? ents[e] : 0u;
    for (; e < e1; e += 4) {
        unsigned tn = (e + 4 < e1) ? ents[e + 4] : 0u;
        float vv = __half2float(__ushort_as_half((unsigned short)(t & 0xffffu)));
        float4 v = *(const float4*)(in + (long long)(t >> 16) * 64 + q * 4);
        if (BN) {
            v.x = fmaxf(fmaf(v.x, sc[0], sh[0]), 0.f) + hb[0];
            v.y = fmaxf(fmaf(v.y, sc[1], sh[1]), 0.f) + hb[1];
            v.z = fmaxf(fmaf(v.z, sc[2], sh[2]), 0.f) + hb[2];
            v.w = fmaxf(fmaf(v.w, sc[3], sh[3]), 0.f) + hb[3];
        }
        acc.x = fmaf(vv, v.x, acc.x);
        acc.y = fmaf(vv, v.y, acc.y);
        acc.z = fmaf(vv, v.z, acc.z);
        acc.w = fmaf(vv, v.w, acc.w);
        t = tn;
    }
    acc.x += __shfl_xor(acc.x, 16, 64); acc.x += __shfl_xor(acc.x, 32, 64);
    acc.y += __shfl_xor(acc.y, 16, 64); acc.y += __shfl_xor(acc.y, 32, 64);
    acc.z += __shfl_xor(acc.z, 16, 64); acc.z += __shfl_xor(acc.z, 32, 64);
    acc.w += __shfl_xor(acc.w, 16, 64); acc.w += __shfl_xor(acc.w, 32, 64);
    if (sub == 0) *(float4*)(out + (long long)node * 64 + q * 4) = acc;
}

// ---- fused tail: softmax -> fc1 -> fusion gate; bn applied to hidden --------
#define TPAD 68
__device__ __forceinline__ float dot4(float4 a, float4 b) {
    return fmaf(a.x, b.x, fmaf(a.y, b.y, fmaf(a.z, b.z, a.w * b.w)));
}

__global__ __launch_bounds__(256) void tail_kernel(const float* __restrict__ x2,
                                                   const float* __restrict__ h2raw,
                                                   const float* __restrict__ fc1_W,
                                                   const float* __restrict__ fusW1,
                                                   const float* __restrict__ b1,
                                                   const float* __restrict__ w2,
                                                   const float* __restrict__ b2,
                                                   const float* __restrict__ stats,
                                                   const float* __restrict__ gamma,
                                                   const float* __restrict__ beta,
                                                   float invN,
                                                   float* __restrict__ out, int n) {
    __shared__ float A[64 * TPAD];    // P (softmax probs), later S (subn)
    __shared__ float Hs[64 * TPAD];   // hidden tile (bn applied)
    __shared__ float WL[64 * TPAD];   // fc1_W, later fus_l1_W
    __shared__ float bsc[64], bsh[64];
    int t = threadIdx.x;
    int tx = t & 15, ty = t >> 4;
    int r0 = blockIdx.x * 64;

    if (t < 64) {
        float mu = stats[t] * invN;
        float var = stats[64 + t] * invN - mu * mu;
        float s = gamma[t] * rsqrtf(var + 1e-5f);
        bsc[t] = s; bsh[t] = beta[t] - mu * s;
    }
    __syncthreads();

    float b1d[4], w2d[4];
#pragma unroll
    for (int di = 0; di < 4; ++di) {
        b1d[di] = b1[tx + 16 * di];
        w2d[di] = w2[tx + 16 * di];
    }
    float b20 = b2[0];

    // fc1 weights -> WL ; bn(hidden) tile -> Hs
    for (int f = t; f < 1024; f += 256) {
        int d = f >> 4, k4 = (f & 15) << 2;
        *(float4*)&WL[d * TPAD + k4] = *(const float4*)&fc1_W[d * 64 + k4];
        int gr = r0 + d;
        float4 hv = make_float4(0.f, 0.f, 0.f, 0.f);
        if (gr < n) {
            hv = *(const float4*)&h2raw[(long long)gr * 64 + k4];
            hv.x = fmaf(hv.x, bsc[k4],     bsh[k4]);
            hv.y = fmaf(hv.y, bsc[k4 + 1], bsh[k4 + 1]);
            hv.z = fmaf(hv.z, bsc[k4 + 2], bsh[k4 + 2]);
            hv.w = fmaf(hv.w, bsc[k4 + 3], bsh[k4 + 3]);
        }
        *(float4*)&Hs[d * TPAD + k4] = hv;
    }

    // x2 tile: load + row softmax -> A
#pragma unroll
    for (int ri = 0; ri < 4; ++ri) {
        int rl = 4 * ty + ri;
        int r = r0 + rl;
        bool ok = r < n;
        float vv[4];
#pragma unroll
        for (int di = 0; di < 4; ++di)
            vv[di] = ok ? x2[(long long)r * 64 + tx + 16 * di] : 0.f;
        float m = fmaxf(fmaxf(vv[0], vv[1]), fmaxf(vv[2], vv[3]));
        for (int s = 1; s < 16; s <<= 1) m = fmaxf(m, __shfl_xor(m, s, 16));
        float e0 = expf(vv[0] - m), e1 = expf(vv[1] - m);
        float e2 = expf(vv[2] - m), e3 = expf(vv[3] - m);
        float sm = e0 + e1 + e2 + e3;
        for (int s = 1; s < 16; s <<= 1) sm += __shfl_xor(sm, s, 16);
        float inv = 1.0f / sm;
        A[rl * TPAD + tx]      = e0 * inv;
        A[rl * TPAD + tx + 16] = e1 * inv;
        A[rl * TPAD + tx + 32] = e2 * inv;
        A[rl * TPAD + tx + 48] = e3 * inv;
    }
    __syncthreads();

    // fc1: sn = P @ fc1_W^T
    float sn[4][4];
#pragma unroll
    for (int ri = 0; ri < 4; ++ri)
#pragma unroll
        for (int di = 0; di < 4; ++di) sn[ri][di] = 0.f;
    for (int k = 0; k < 64; k += 4) {
        float4 p4[4], w4[4];
#pragma unroll
        for (int ri = 0; ri < 4; ++ri) p4[ri] = *(float4*)&A[(4 * ty + ri) * TPAD + k];
#pragma unroll
        for (int di = 0; di < 4; ++di) w4[di] = *(float4*)&WL[(tx + 16 * di) * TPAD + k];
#pragma unroll
        for (int ri = 0; ri < 4; ++ri)
#pragma unroll
            for (int di = 0; di < 4; ++di)
                sn[ri][di] += dot4(p4[ri], w4[di]);
    }
    __syncthreads();

    // S (subn) -> A ; fus_l1_W -> WL
#pragma unroll
    for (int ri = 0; ri < 4; ++ri)
#pragma unroll
        for (int di = 0; di < 4; ++di)
            A[(4 * ty + ri) * TPAD + tx + 16 * di] = sn[ri][di];
    for (int f = t; f < 1024; f += 256) {
        int d = f >> 4, k4 = (f & 15) << 2;
        *(float4*)&WL[d * TPAD + k4] = *(const float4*)&fusW1[d * 64 + k4];
    }
    __syncthreads();

    // gates
    float aH[4][4], aS[4][4];
#pragma unroll
    for (int ri = 0; ri < 4; ++ri)
#pragma unroll
        for (int di = 0; di < 4; ++di) { aH[ri][di] = b1d[di]; aS[ri][di] = b1d[di]; }
    for (int k = 0; k < 64; k += 4) {
        float4 h4[4], s4[4], w4[4];
#pragma unroll
        for (int ri = 0; ri < 4; ++ri) {
            h4[ri] = *(float4*)&Hs[(4 * ty + ri) * TPAD + k];
            s4[ri] = *(float4*)&A[(4 * ty + ri) * TPAD + k];
        }
#pragma unroll
        for (int di = 0; di < 4; ++di) w4[di] = *(float4*)&WL[(tx + 16 * di) * TPAD + k];
#pragma unroll
        for (int ri = 0; ri < 4; ++ri)
#pragma unroll
            for (int di = 0; di < 4; ++di) {
                aH[ri][di] += dot4(h4[ri], w4[di]);
                aS[ri][di] += dot4(s4[ri], w4[di]);
            }
    }

#pragma unroll
    for (int ri = 0; ri < 4; ++ri) {
        int rl = 4 * ty + ri;
        int r = r0 + rl;
        float pH = 0.f, pS = 0.f;
#pragma unroll
        for (int di = 0; di < 4; ++di) {
            pH = fmaf(tanhf(aH[ri][di]), w2d[di], pH);
            pS = fmaf(tanhf(aS[ri][di]), w2d[di], pS);
        }
        for (int s = 1; s < 16; s <<= 1) {
            pH += __shfl_xor(pH, s, 16);
            pS += __shfl_xor(pS, s, 16);
        }
        pH += b20; pS += b20;
        float mx = fmaxf(pH, pS);
        float eH = expf(pH - mx), eS = expf(pS - mx);
        float inv = 1.0f / (eH + eS);
        if (r < n) {
#pragma unroll
            for (int di = 0; di < 4; ++di) {
                int d = tx + 16 * di;
                float hv = Hs[rl * TPAD + d];
                out[(long long)r * 64 + d] = (eH * hv + eS * sn[ri][di]) * inv;
            }
        }
    }
}

// ---------------------------------------------------------------------------
extern "C" void kernel_launch(void* const* d_in, const int* in_sizes, int n_in,
                              void* d_out, int out_size, void* d_ws, size_t ws_size,
                              hipStream_t stream) {
    const float* emb       = (const float*)d_in[0];
    const float* W1        = (const float*)d_in[1];
    const float* b1        = (const float*)d_in[2];
    const float* W2        = (const float*)d_in[3];
    const float* b2        = (const float*)d_in[4];
    const float* gamma     = (const float*)d_in[5];
    const float* beta      = (const float*)d_in[6];
    const float* hgc1_bias = (const float*)d_in[7];
    const float* fc1_W     = (const float*)d_in[8];
    const float* fus_l1_W  = (const float*)d_in[9];
    const float* fus_l1_b  = (const float*)d_in[10];
    const float* fus_l2_W  = (const float*)d_in[11];
    const float* fus_l2_b  = (const float*)d_in[12];
    const float* hg_val    = (const float*)d_in[13];
    const int*   edge_index= (const int*)d_in[14];
    const int*   hg_row    = (const int*)d_in[15];
    const int*   hg_col    = (const int*)d_in[16];

    const int N   = in_sizes[0] / 64;
    const int E   = in_sizes[14] / 2;
    const int NNZ = in_sizes[13];
    const int Np  = (N + 3) & ~3;            // 16B-aligned strides
    const int keyspan = (N + SEGS - 1) / SEGS;
    const int PB = (N + SCHUNK - 1) / SCHUNK;   // scan blocks per array (<=64 for wave base)
    const int* src = edge_index;
    const int* dst = edge_index + E;

    // workspace layout (4B units, all offsets multiples of 4):
    // dinv Np | sdi Np | w12 4096 | bw 64 |
    // Z: [stats 128 | gcn_cnt Np | hgc_cnt Np | hgr_cnt Np]   <- single memset
    // gcn_off Np+4 | hgc_off Np+4 | hgr_off Np+4 | partials 3*64 |
    // gcn_srcs E/2 (u16) | hgc_ent NNZ | hgr_ent NNZ | buf1 128*Np | buf2 64*Np
    float* ws      = (float*)d_ws;
    float* dinv    = ws;
    float* sdi     = dinv + Np;
    float* w12     = sdi + Np;
    float* bw      = w12 + 4096;
    float* stats   = bw + 64;
    int*   gcn_cnt = (int*)(stats + 128);
    int*   hgc_cnt = gcn_cnt + Np;
    int*   hgr_cnt = hgc_cnt + Np;
    int*   gcn_off = hgr_cnt + Np;
    int*   hgc_off = gcn_off + (Np + 4);
    int*   hgr_off = hgc_off + (Np + 4);
    int*   partials= hgr_off + (Np + 4);
    unsigned short* gcn_srcs = (unsigned short*)(partials + 192);
    unsigned* hgc_ent = (unsigned*)(gcn_srcs + ((E + 1) & ~1));
    unsigned* hgr_ent = hgc_ent + NNZ;
    float* buf1    = (float*)(hgr_ent + NNZ);
    float* buf2    = buf1 + (size_t)128 * Np;

    float* tbuf = buf2;                      // A-hat emb        N x 64
    float* ubuf = buf1;                      // A-hat^2 emb      N x 64
    float* h2   = buf1 + (size_t)64 * Np;    // raw h2 (pre-bn)  N x 64
    float* eemb = buf2;                      // edge emb         N x 64 (tbuf dead)
    float* x2   = buf1;                      // HGNN out         N x 64 (ubuf dead)
    float* out  = (float*)d_out;

    const float invN = 1.0f / (float)N;

    // --- CSR builds (XCD-local segmented; decoupled two-phase scan) ---
    hipMemsetAsync(stats, 0, (size_t)(128 + 3 * Np) * sizeof(int), stream);
    hist_all_kernel<<<SEGS * SEGBLK, 256, 0, stream>>>(dst, E, hg_row, hg_col, NNZ,
                                                       gcn_cnt, hgr_cnt, hgc_cnt, keyspan);
    scan_part_kernel<<<3 * PB, 256, 0, stream>>>(gcn_cnt, hgc_cnt, hgr_cnt, partials, N, PB);
    scan_apply_kernel<<<3 * PB, 256, 0, stream>>>(gcn_cnt, gcn_off, hgc_cnt, hgc_off,
                                                  hgr_cnt, hgr_off, partials, dinv, N, PB);
    place_all_kernel<<<SEGS * SEGBLK, 256, 0, stream>>>(src, dst, gcn_cnt, gcn_srcs, E,
                                                        hg_row, hg_col, hg_val,
                                                        hgc_cnt, hgr_cnt,
                                                        hgc_ent, hgr_ent, NNZ, keyspan);

    // --- weight precompute + reassociated GCN ---
    wprep_kernel<<<65, 64, 0, stream>>>(W1, W2, b1, w12, bw);
    gcn_gather_kernel<true><<<(N + 3) / 4, 256, 0, stream>>>(emb, dinv, gcn_off, gcn_srcs,
                                                             tbuf, sdi, N);
    gcn_gather_kernel<false><<<(N + 3) / 4, 256, 0, stream>>>(tbuf, dinv, gcn_off, gcn_srcs,
                                                              ubuf, nullptr, N);
    gemm_h2_kernel<<<(N + 31) / 32, 256, 0, stream>>>(ubuf, w12, bw, b2, sdi, h2, N);

    // --- BatchNorm stats (apply is fused into consumers) ---
    {
        int nblocks = 256;
        int rpb = (N + nblocks - 1) / nblocks;
        bn_stats_kernel<<<nblocks, 256, 0, stream>>>(h2, stats, N, rpb);
    }

    // --- HGNN: edge_emb = G^T relu(bn(h2))+bias ; x2 = G edge_emb ---
    hg_gather_kernel<true><<<(N + 3) / 4, 256, 0, stream>>>(h2, hgc_off, hgc_ent,
                                                            stats, gamma, beta, hgc1_bias,
                                                            invN, eemb, N);
    hg_gather_kernel<false><<<(N + 3) / 4, 256, 0, stream>>>(eemb, hgr_off, hgr_ent,
                                                             nullptr, nullptr, nullptr, nullptr,
                                                             0.f, x2, N);

    // --- fused softmax + fc1 + fusion gate (bn on hidden inline) ---
    tail_kernel<<<(N + 63) / 64, 256, 0, stream>>>(x2, h2, fc1_W, fus_l1_W, fus_l1_b,
                                                   fus_l2_W, fus_l2_b, stats, gamma, beta,
                                                   invN, out, N);
}